// Round 6
// baseline (522.702 us; speedup 1.0000x reference)
//
#include <hip/hip_runtime.h>
#include <hip/hip_bf16.h>

#define EPS   1e-5f
#define NH    4      // heads
#define DIN   128
#define DHID  64
#define DOUT  32
#define CAP   128    // per-wave LDS edge capacity in k_agg
#define GM    32     // rows per MFMA gemm block
#define NBUCK 64     // partition buckets (dst >> bshift)
#define BSTR  16     // bcur stride (ints) = one 64B line per bucket
#define EPT   16     // edges per thread in k_part
#define EPB   (256 * EPT)   // 4096 edges per k_part block

typedef __attribute__((ext_vector_type(8))) short short8;   // 8 bf16 (4 VGPRs)
typedef __attribute__((ext_vector_type(4))) float f32x4;    // MFMA accumulator
typedef __attribute__((ext_vector_type(2))) float f32x2;    // fp8 cvt result / packed fma

__device__ __forceinline__ float us2f(unsigned short u) {   // raw bf16 bits -> f32
    return __uint_as_float((unsigned)u << 16);
}
__device__ __forceinline__ unsigned short f2us(float v) {   // f32 -> bf16 bits (RN)
    __hip_bfloat16 hb = __float2bfloat16(v);
    return *(unsigned short*)&hb;
}
__device__ __forceinline__ unsigned char f2e4m3(float v) {  // f32 -> fp8 e4m3 (HW, OCP)
    int p = __builtin_amdgcn_cvt_pk_fp8_f32(v, 0.f, 0, false);
    return (unsigned char)(p & 0xff);
}
__device__ __forceinline__ float lrelu(float a) { return (a >= 0.f) ? a : 0.2f * a; }

// ---------------------------------------------------------------- fused init + weight prep
// deg preset to 1 (self-loop pre-counted); BN1 and BN2 folded to scale/shift
__global__ __launch_bounds__(256) void k_setup(
    int* __restrict__ deg, float* __restrict__ pool, int* __restrict__ bcur,
    int N, int npool,
    const float* __restrict__ ing, const float* __restrict__ inb,
    const float* __restrict__ inm, const float* __restrict__ inv,
    const float* __restrict__ W1, const float* __restrict__ W2,
    const float* __restrict__ as1, const float* __restrict__ ad1,
    const float* __restrict__ as2, const float* __restrict__ ad2,
    const float* __restrict__ b1,
    const float* __restrict__ bn1g, const float* __restrict__ bn1b,
    const float* __restrict__ bn1m, const float* __restrict__ bn1v,
    const float* __restrict__ b2,
    const float* __restrict__ bn2g, const float* __restrict__ bn2b,
    const float* __restrict__ bn2m, const float* __restrict__ bn2v,
    unsigned short* __restrict__ Wt, unsigned short* __restrict__ Wt2,
    unsigned short* __restrict__ Wast1, unsigned short* __restrict__ Wast2,
    float* __restrict__ scl1, float* __restrict__ shf1,
    float* __restrict__ scl2, float* __restrict__ shf2,
    float* __restrict__ sclX, float* __restrict__ shfX)
{
    int g = blockIdx.x * blockDim.x + threadIdx.x;
    if (g < N) deg[g] = 1;                   // self-loop pre-counted
    if (g < npool) pool[g] = 0.f;            // zeroes pool AND cnt (contiguous)
    if (g < NBUCK * BSTR) bcur[g] = 0;
    if (g < 256 * DIN) {   // Wt[n][k] = W1[k][n]
        int n = g >> 7, k = g & 127;
        Wt[g] = f2us(W1[(size_t)k * 256 + n]);
    }
    if (g < 256 * DHID) {  // Wt2[n][k] = W2[k][n]
        int n = g >> 6, k = g & 63;
        Wt2[g] = f2us(W2[(size_t)k * 256 + n]);
    }
    if (g < 16 * DIN) {    // Wast1[c][k]: c<4 -> W1·as1 head c ; 4..7 -> W1·ad1 ; 8..15 -> 0
        int c = g >> 7, k = g & 127;
        float s = 0.f;
        if (c < 4)      { for (int j = 0; j < 64; ++j) s += W1[(size_t)k * 256 + c * 64 + j] * as1[c * 64 + j]; }
        else if (c < 8) { for (int j = 0; j < 64; ++j) s += W1[(size_t)k * 256 + (c - 4) * 64 + j] * ad1[(c - 4) * 64 + j]; }
        Wast1[g] = f2us(s);
    }
    if (g < 16 * DHID) {   // Wast2[c][k]
        int c = g >> 6, k = g & 63;
        float s = 0.f;
        if (c < 4)      { for (int j = 0; j < 64; ++j) s += W2[(size_t)k * 256 + c * 64 + j] * as2[c * 64 + j]; }
        else if (c < 8) { for (int j = 0; j < 64; ++j) s += W2[(size_t)k * 256 + (c - 4) * 64 + j] * ad2[(c - 4) * 64 + j]; }
        Wast2[g] = f2us(s);
    }
    if (g < DHID) {        // fold b1 + BN1 into scale/shift
        float sc = bn1g[g] * rsqrtf(bn1v[g] + EPS);
        scl1[g] = sc;
        shf1[g] = (b1[g] - bn1m[g]) * sc + bn1b[g];
        float sc2 = bn2g[g] * rsqrtf(bn2v[g] + EPS);   // fold b2 + BN2 (for fused pool)
        scl2[g] = sc2;
        shf2[g] = (b2[g] - bn2m[g]) * sc2 + bn2b[g];
    }
    if (g < DIN) {         // fold input BN into scale/shift (for k_gemm1)
        float sc = ing[g] * rsqrtf(inv[g] + EPS);
        sclX[g] = sc;
        shfX[g] = inb[g] - inm[g] * sc;
    }
}

// ---------------------------------------------------------------- scan phase A: per-block exclusive scan
__global__ __launch_bounds__(256) void k_scan_a(const int* __restrict__ deg,
                                                int* __restrict__ rowptr,
                                                int* __restrict__ bsum, int N) {
    __shared__ int sh[256];
    const int t = threadIdx.x;
    const int i = blockIdx.x * 256 + t;
    int v = (i < N) ? deg[i] : 0;
    sh[t] = v;
    __syncthreads();
    #pragma unroll
    for (int o = 1; o < 256; o <<= 1) {
        int u = (t >= o) ? sh[t - o] : 0;
        __syncthreads();
        sh[t] += u;
        __syncthreads();
    }
    if (i < N) rowptr[i] = sh[t] - v;
    if (t == 255) bsum[blockIdx.x] = sh[255];
}

// ---------------------------------------------------------------- scan phase B+C merged
__global__ __launch_bounds__(256) void k_scan_c2(int* __restrict__ rowptr,
                                                 int* __restrict__ cursor,
                                                 const int* __restrict__ bsum,
                                                 int N, int Etot, int nb) {
    __shared__ int sh[256];
    const int t = threadIdx.x;
    int v = (t < nb) ? bsum[t] : 0;
    sh[t] = v;
    __syncthreads();
    #pragma unroll
    for (int o = 1; o < 256; o <<= 1) {
        int u = (t >= o) ? sh[t - o] : 0;
        __syncthreads();
        sh[t] += u;
        __syncthreads();
    }
    const int off = (blockIdx.x > 0) ? sh[blockIdx.x - 1] : 0;
    const int i = blockIdx.x * 256 + t;
    if (i < N) {
        int r = rowptr[i] + off;
        rowptr[i] = r;
        cursor[i] = r;
    }
    if (i == 0) rowptr[N] = Etot;
}

// ---------------------------------------------------------------- CSR fill phase A: bucket partition + deg hist
// self-loop tail also builds the per-group node-count histogram (for the fused pool)
__global__ __launch_bounds__(256) void k_part(
    const int* __restrict__ ei, int E, int N, int bshift,
    unsigned long long* __restrict__ arena, int* __restrict__ bcur,
    int* __restrict__ deg, int cap,
    const int* __restrict__ batch, float* __restrict__ cnt)
{
    __shared__ int lhist[NBUCK];
    __shared__ int lbase[NBUCK];
    const int t = threadIdx.x;
    const int e0 = blockIdx.x * EPB;
    const int eEnd = min(e0 + EPB, E + N);

    if (t < NBUCK) lhist[t] = 0;
    __syncthreads();

    int myb[EPT], myd[EPT], mys[EPT];
    #pragma unroll
    for (int r = 0; r < EPT; ++r) {
        int e = e0 + r * 256 + t;
        myb[r] = -1;
        if (e < eEnd) {
            int s, d;
            if (e < E) { s = ei[e]; d = ei[E + e]; atomicAdd(&deg[d], 1); }
            else {
                s = d = e - E;                       // self-loop: deg pre-set to 1 in setup
                atomicAdd(&cnt[batch[s]], 1.f);      // group-size histogram
            }
            int b = d >> bshift;
            myb[r] = b; myd[r] = d; mys[r] = s;
            atomicAdd(&lhist[b], 1);
        }
    }
    __syncthreads();

    if (t < NBUCK) {
        int c = lhist[t];
        lbase[t] = c ? atomicAdd(&bcur[t * BSTR], c) : 0;   // one line per bucket
        lhist[t] = 0;     // reuse as local bump
    }
    __syncthreads();

    #pragma unroll
    for (int r = 0; r < EPT; ++r) {
        int b = myb[r];
        if (b >= 0) {
            int li = atomicAdd(&lhist[b], 1);
            int pos = lbase[b] + li;
            if (pos >= cap) pos = cap - 1;    // safety (statistically unreachable)
            arena[(size_t)b * cap + pos] =
                ((unsigned long long)(unsigned)myd[r] << 32) | (unsigned)mys[r];
        }
    }
}

// ---------------------------------------------------------------- CSR fill phase B: bucket-local scatter
__global__ __launch_bounds__(256) void k_fill2(
    const unsigned long long* __restrict__ arena, const int* __restrict__ bcur,
    int cap, int* __restrict__ cursor, int* __restrict__ col)
{
    const int b = blockIdx.x;
    const int idx = blockIdx.y * 256 + threadIdx.x;
    if (idx >= bcur[b * BSTR]) return;
    unsigned long long v = arena[(size_t)b * cap + idx];
    int d = (int)(v >> 32);
    int s = (int)(v & 0xffffffffu);
    int pos = atomicAdd(&cursor[d], 1);
    col[pos] = s;
}

// ---------------------------------------------------------------- layer-1 GEMM via MFMA (input BN fused)
__global__ __launch_bounds__(256) void k_gemm1(
    const float* __restrict__ x,             // [N][128] f32
    const float* __restrict__ sclX, const float* __restrict__ shfX,
    const unsigned short* __restrict__ Wt,   // [256][128] bf16
    const unsigned short* __restrict__ Wast, // [16][128] bf16 (cols 8..15 zero)
    unsigned char* __restrict__ h,           // [N][256] fp8 (transposed [n][c][hd])
    float* __restrict__ asrc, float* __restrict__ adst, int N)
{
    __shared__ float Csh[GM][260];
    const int t = threadIdx.x;
    const int lane = t & 63, wv = t >> 6;
    const int qm = lane & 15, qd = lane >> 4;
    const int base = blockIdx.x * GM;

    short8 afr[2][4];
    #pragma unroll
    for (int ks = 0; ks < 4; ++ks) {
        const int k0 = qd * 8 + ks * 32;
        float4 s0 = *(const float4*)(sclX + k0), s1 = *(const float4*)(sclX + k0 + 4);
        float4 h0 = *(const float4*)(shfX + k0), h1 = *(const float4*)(shfX + k0 + 4);
        #pragma unroll
        for (int rt = 0; rt < 2; ++rt) {
            int node = base + rt * 16 + qm;
            if (node >= N) node = N - 1;
            const float* xp = x + (size_t)node * DIN + k0;
            float4 x0 = *(const float4*)xp, x1 = *(const float4*)(xp + 4);
            short8 v;
            v[0] = f2us(x0.x * s0.x + h0.x); v[1] = f2us(x0.y * s0.y + h0.y);
            v[2] = f2us(x0.z * s0.z + h0.z); v[3] = f2us(x0.w * s0.w + h0.w);
            v[4] = f2us(x1.x * s1.x + h1.x); v[5] = f2us(x1.y * s1.y + h1.y);
            v[6] = f2us(x1.z * s1.z + h1.z); v[7] = f2us(x1.w * s1.w + h1.w);
            afr[rt][ks] = v;
        }
    }

    const int n0 = wv * 64;
    f32x4 acc[2][4];
    #pragma unroll
    for (int rt = 0; rt < 2; ++rt)
        #pragma unroll
        for (int ct = 0; ct < 4; ++ct)
            acc[rt][ct] = (f32x4){0.f, 0.f, 0.f, 0.f};

    #pragma unroll
    for (int ct = 0; ct < 4; ++ct) {
        const unsigned short* bp = Wt + (size_t)(n0 + ct * 16 + qm) * DIN + qd * 8;
        #pragma unroll
        for (int ks = 0; ks < 4; ++ks) {
            short8 bfr = *(const short8*)(bp + ks * 32);
            acc[0][ct] = __builtin_amdgcn_mfma_f32_16x16x32_bf16(afr[0][ks], bfr, acc[0][ct], 0, 0, 0);
            acc[1][ct] = __builtin_amdgcn_mfma_f32_16x16x32_bf16(afr[1][ks], bfr, acc[1][ct], 0, 0, 0);
        }
    }

    // fused attention logits: [asrc|adst] = A @ Wast^T (reuses afr)
    {
        const unsigned short* wp = Wast + (size_t)qm * DIN + qd * 8;
        f32x4 aat[2];
        aat[0] = (f32x4){0.f, 0.f, 0.f, 0.f};
        aat[1] = (f32x4){0.f, 0.f, 0.f, 0.f};
        #pragma unroll
        for (int ks = 0; ks < 4; ++ks) {
            short8 wfr = *(const short8*)(wp + ks * 32);
            aat[0] = __builtin_amdgcn_mfma_f32_16x16x32_bf16(afr[0][ks], wfr, aat[0], 0, 0, 0);
            aat[1] = __builtin_amdgcn_mfma_f32_16x16x32_bf16(afr[1][ks], wfr, aat[1], 0, 0, 0);
        }
        const int c = qm;   // C layout: col = lane&15, row = qd*4+rg
        #pragma unroll
        for (int rt = 0; rt < 2; ++rt)
            #pragma unroll
            for (int rg = 0; rg < 4; ++rg) {
                int nd = base + rt * 16 + qd * 4 + rg;
                if (nd < N) {
                    if (c < 4)      asrc[nd * 4 + c] = aat[rt][rg];
                    else if (c < 8) adst[nd * 4 + (c - 4)] = aat[rt][rg];
                }
            }
    }

    #pragma unroll
    for (int rt = 0; rt < 2; ++rt)
        #pragma unroll
        for (int ct = 0; ct < 4; ++ct)
            #pragma unroll
            for (int rg = 0; rg < 4; ++rg)
                Csh[rt * 16 + qd * 4 + rg][n0 + ct * 16 + qm] = acc[rt][ct][rg];
    __syncthreads();

    const int hcol = ((t & 3) << 6) | (t >> 2);   // h[n][t] <- C[n][(t&3)*64 + (t>>2)]
    for (int r = 0; r < GM; ++r) {
        int node = base + r;
        if (node >= N) break;
        h[(size_t)node * 256 + t] = f2e4m3(Csh[r][hcol]);
    }
}

// ---------------------------------------------------------------- layer-2 GEMM via MFMA (K=64)
__global__ __launch_bounds__(256) void k_gemm2(
    const unsigned short* __restrict__ A2,   // [N][64] bf16
    const unsigned short* __restrict__ Wt2,  // [256][64] bf16
    const unsigned short* __restrict__ Wast, // [16][64] bf16
    unsigned char* __restrict__ h,
    float* __restrict__ asrc, float* __restrict__ adst, int N)
{
    __shared__ float Csh[GM][260];
    const int t = threadIdx.x;
    const int lane = t & 63, wv = t >> 6;
    const int qm = lane & 15, qd = lane >> 4;
    const int base = blockIdx.x * GM;

    short8 afr[2][2];
    #pragma unroll
    for (int rt = 0; rt < 2; ++rt) {
        int node = base + rt * 16 + qm;
        if (node >= N) node = N - 1;
        const unsigned short* ap = A2 + (size_t)node * DHID + qd * 8;
        #pragma unroll
        for (int ks = 0; ks < 2; ++ks)
            afr[rt][ks] = *(const short8*)(ap + ks * 32);
    }

    const int n0 = wv * 64;
    f32x4 acc[2][4];
    #pragma unroll
    for (int rt = 0; rt < 2; ++rt)
        #pragma unroll
        for (int ct = 0; ct < 4; ++ct)
            acc[rt][ct] = (f32x4){0.f, 0.f, 0.f, 0.f};

    #pragma unroll
    for (int ct = 0; ct < 4; ++ct) {
        const unsigned short* bp = Wt2 + (size_t)(n0 + ct * 16 + qm) * DHID + qd * 8;
        #pragma unroll
        for (int ks = 0; ks < 2; ++ks) {
            short8 bfr = *(const short8*)(bp + ks * 32);
            acc[0][ct] = __builtin_amdgcn_mfma_f32_16x16x32_bf16(afr[0][ks], bfr, acc[0][ct], 0, 0, 0);
            acc[1][ct] = __builtin_amdgcn_mfma_f32_16x16x32_bf16(afr[1][ks], bfr, acc[1][ct], 0, 0, 0);
        }
    }

    // fused attention logits
    {
        const unsigned short* wp = Wast + (size_t)qm * DHID + qd * 8;
        f32x4 aat[2];
        aat[0] = (f32x4){0.f, 0.f, 0.f, 0.f};
        aat[1] = (f32x4){0.f, 0.f, 0.f, 0.f};
        #pragma unroll
        for (int ks = 0; ks < 2; ++ks) {
            short8 wfr = *(const short8*)(wp + ks * 32);
            aat[0] = __builtin_amdgcn_mfma_f32_16x16x32_bf16(afr[0][ks], wfr, aat[0], 0, 0, 0);
            aat[1] = __builtin_amdgcn_mfma_f32_16x16x32_bf16(afr[1][ks], wfr, aat[1], 0, 0, 0);
        }
        const int c = qm;
        #pragma unroll
        for (int rt = 0; rt < 2; ++rt)
            #pragma unroll
            for (int rg = 0; rg < 4; ++rg) {
                int nd = base + rt * 16 + qd * 4 + rg;
                if (nd < N) {
                    if (c < 4)      asrc[nd * 4 + c] = aat[rt][rg];
                    else if (c < 8) adst[nd * 4 + (c - 4)] = aat[rt][rg];
                }
            }
    }

    #pragma unroll
    for (int rt = 0; rt < 2; ++rt)
        #pragma unroll
        for (int ct = 0; ct < 4; ++ct)
            #pragma unroll
            for (int rg = 0; rg < 4; ++rg)
                Csh[rt * 16 + qd * 4 + rg][n0 + ct * 16 + qm] = acc[rt][ct][rg];
    __syncthreads();

    const int hcol = ((t & 3) << 6) | (t >> 2);
    for (int r = 0; r < GM; ++r) {
        int node = base + r;
        if (node >= N) break;
        h[(size_t)node * 256 + t] = f2e4m3(Csh[r][hcol]);
    }
}

// ---------------------------------------------------------------- pull-style GAT aggregation (fp8 h)
// Pass B: lane = channel-dword; 4 independent 64-lane dword gathers per iteration;
// head-pair accumulation via packed f32x2 FMA (v_pk_fma_f32).
// mode 1: write bf16 A2 (bias+BN1+ReLU). mode 0: fused pool — BN2+ReLU+atomicAdd to pool[batch[d]].
__global__ __launch_bounds__(256) void k_agg(
    const int* __restrict__ rowptr, const int* __restrict__ col,
    const float* __restrict__ asrc, const float* __restrict__ adst,
    const unsigned char* __restrict__ h8,
    float* __restrict__ pool, unsigned short* __restrict__ outb,
    const int* __restrict__ batch,
    const float* __restrict__ scl, const float* __restrict__ shf,
    int mode, int N)
{
    __shared__ float4 exs[4][CAP];
    __shared__ int    cols[4][CAP];
    const int lane = threadIdx.x & 63;
    const int wv   = threadIdx.x >> 6;
    const int d = (blockIdx.x << 2) + wv;
    if (d >= N) return;
    const int r0  = rowptr[d];
    const int deg = rowptr[d + 1] - r0;        // >= 1 (self-loop)

    const float4 ad4 = ((const float4*)adst)[d];
    const float4* __restrict__ as4 = (const float4*)asrc;

    // pass A: exp(lrelu(logit)) -> LDS, per-head sum
    float sm0 = 0.f, sm1 = 0.f, sm2 = 0.f, sm3 = 0.f;
    for (int j = lane; j < deg; j += 64) {
        int s = col[r0 + j];
        float4 a = as4[s];
        float e0 = __expf(lrelu(a.x + ad4.x));
        float e1 = __expf(lrelu(a.y + ad4.y));
        float e2 = __expf(lrelu(a.z + ad4.z));
        float e3 = __expf(lrelu(a.w + ad4.w));
        if (j < CAP) { cols[wv][j] = s; exs[wv][j] = make_float4(e0, e1, e2, e3); }
        sm0 += e0; sm1 += e1; sm2 += e2; sm3 += e3;
    }
    #pragma unroll
    for (int o = 1; o < 64; o <<= 1) {
        sm0 += __shfl_xor(sm0, o, 64);
        sm1 += __shfl_xor(sm1, o, 64);
        sm2 += __shfl_xor(sm2, o, 64);
        sm3 += __shfl_xor(sm3, o, 64);
    }
    const float i0 = 0.25f / sm0, i1 = 0.25f / sm1, i2 = 0.25f / sm2, i3 = 0.25f / sm3;

    // pass B: packed head-pair accumulation (2 chains for ILP)
    const unsigned int* __restrict__ hu = (const unsigned int*)h8;
    f32x2 accA01 = {0.f, 0.f}, accA23 = {0.f, 0.f};
    f32x2 accB01 = {0.f, 0.f}, accB23 = {0.f, 0.f};
    if (deg <= CAP) {
        int j = 0;
        for (; j + 3 < deg; j += 4) {
            int sA = cols[wv][j],     sB = cols[wv][j + 1];
            int sC = cols[wv][j + 2], sD = cols[wv][j + 3];
            unsigned int vA = hu[(size_t)sA * 64 + lane];
            unsigned int vB = hu[(size_t)sB * 64 + lane];
            unsigned int vC = hu[(size_t)sC * 64 + lane];
            unsigned int vD = hu[(size_t)sD * 64 + lane];
            float4 wA = exs[wv][j],     wB = exs[wv][j + 1];
            float4 wC = exs[wv][j + 2], wD = exs[wv][j + 3];
            f32x2 lA = __builtin_amdgcn_cvt_pk_f32_fp8(vA, false), hA = __builtin_amdgcn_cvt_pk_f32_fp8(vA, true);
            f32x2 lB = __builtin_amdgcn_cvt_pk_f32_fp8(vB, false), hB = __builtin_amdgcn_cvt_pk_f32_fp8(vB, true);
            f32x2 lC = __builtin_amdgcn_cvt_pk_f32_fp8(vC, false), hC = __builtin_amdgcn_cvt_pk_f32_fp8(vC, true);
            f32x2 lD = __builtin_amdgcn_cvt_pk_f32_fp8(vD, false), hD = __builtin_amdgcn_cvt_pk_f32_fp8(vD, true);
            accA01 += (f32x2){wA.x, wA.y} * lA; accA23 += (f32x2){wA.z, wA.w} * hA;
            accB01 += (f32x2){wB.x, wB.y} * lB; accB23 += (f32x2){wB.z, wB.w} * hB;
            accA01 += (f32x2){wC.x, wC.y} * lC; accA23 += (f32x2){wC.z, wC.w} * hC;
            accB01 += (f32x2){wD.x, wD.y} * lD; accB23 += (f32x2){wD.z, wD.w} * hD;
        }
        for (; j < deg; ++j) {
            int s = cols[wv][j];
            unsigned int v = hu[(size_t)s * 64 + lane];
            float4 w = exs[wv][j];
            f32x2 lo = __builtin_amdgcn_cvt_pk_f32_fp8(v, false), hi = __builtin_amdgcn_cvt_pk_f32_fp8(v, true);
            accA01 += (f32x2){w.x, w.y} * lo; accA23 += (f32x2){w.z, w.w} * hi;
        }
    } else {                                     // rare: deg > CAP, recompute weights
        for (int j = 0; j < deg; ++j) {
            int s; float4 w;
            if (j < CAP) { s = cols[wv][j]; w = exs[wv][j]; }
            else {
                s = col[r0 + j];
                float4 a = as4[s];
                w.x = __expf(lrelu(a.x + ad4.x)); w.y = __expf(lrelu(a.y + ad4.y));
                w.z = __expf(lrelu(a.z + ad4.z)); w.w = __expf(lrelu(a.w + ad4.w));
            }
            unsigned int v = hu[(size_t)s * 64 + lane];
            f32x2 lo = __builtin_amdgcn_cvt_pk_f32_fp8(v, false), hi = __builtin_amdgcn_cvt_pk_f32_fp8(v, true);
            accA01 += (f32x2){w.x, w.y} * lo; accA23 += (f32x2){w.z, w.w} * hi;
        }
    }
    f32x2 s01 = accA01 + accB01;
    f32x2 s23 = accA23 + accB23;
    float acc = s01.x * i0 + s01.y * i1 + s23.x * i2 + s23.y * i3;

    if (mode) {
        float v = fmaxf(acc * scl[lane] + shf[lane], 0.f);
        outb[(size_t)d * 64 + lane] = f2us(v);
    } else {
        // fused global-mean-pool: BN2 + ReLU + atomic accumulate per graph
        int gr = batch[d];
        float v = fmaxf(acc * scl[lane] + shf[lane], 0.f);
        atomicAdd(&pool[(size_t)gr * 64 + lane], v);
    }
}

// ---------------------------------------------------------------- head
__global__ void k_head(const float* __restrict__ pool, const float* __restrict__ cnt,
                       const float* __restrict__ fc1w, const float* __restrict__ fc1b,
                       const float* __restrict__ fc2w, const float* __restrict__ fc2b,
                       float* __restrict__ out)
{
    int g = blockIdx.x;
    int t = threadIdx.x;  // 64 threads
    __shared__ float emb[64];
    __shared__ float z1[32];
    float c = fmaxf(cnt[g], 1.0f);
    emb[t] = pool[g * 64 + t] / c;
    __syncthreads();
    if (t < 32) {
        float s = fc1b[t];
        for (int k = 0; k < 64; ++k) s += emb[k] * fc1w[k * 32 + t];
        z1[t] = fmaxf(s, 0.f);
    }
    __syncthreads();
    if (t < 32) {
        float o = fc2b[t];
        for (int j = 0; j < 32; ++j) o += z1[j] * fc2w[j * 32 + t];
        out[g * 32 + t] = o;
    }
}

// ---------------------------------------------------------------- launch
extern "C" void kernel_launch(void* const* d_in, const int* in_sizes, int n_in,
                              void* d_out, int out_size, void* d_ws, size_t ws_size,
                              hipStream_t stream)
{
    const float* x    = (const float*)d_in[0];
    const int*   ei   = (const int*)d_in[1];
    const int*   batch= (const int*)d_in[2];
    const float* ing  = (const float*)d_in[3];
    const float* inb  = (const float*)d_in[4];
    const float* inm  = (const float*)d_in[5];
    const float* inv  = (const float*)d_in[6];
    const float* W1   = (const float*)d_in[7];
    const float* as1  = (const float*)d_in[8];
    const float* ad1  = (const float*)d_in[9];
    const float* b1   = (const float*)d_in[10];
    const float* bn1g = (const float*)d_in[11];
    const float* bn1b = (const float*)d_in[12];
    const float* bn1m = (const float*)d_in[13];
    const float* bn1v = (const float*)d_in[14];
    const float* W2   = (const float*)d_in[15];
    const float* as2  = (const float*)d_in[16];
    const float* ad2  = (const float*)d_in[17];
    const float* b2   = (const float*)d_in[18];
    const float* bn2g = (const float*)d_in[19];
    const float* bn2b = (const float*)d_in[20];
    const float* bn2m = (const float*)d_in[21];
    const float* bn2v = (const float*)d_in[22];
    const float* fc1w = (const float*)d_in[23];
    const float* fc1b = (const float*)d_in[24];
    const float* fc2w = (const float*)d_in[25];
    const float* fc2b = (const float*)d_in[26];

    const int N = in_sizes[0] / DIN;
    const int E = in_sizes[1] / 2;
    const int G = out_size / DOUT;
    const int Etot = E + N;

    // bucket shift: smallest with (N-1)>>bshift < NBUCK
    int bshift = 0;
    while ((N >> bshift) >= NBUCK) ++bshift;
    // per-bucket arena capacity: expected density * 1.25 + slack
    const int cap = (int)(((long long)Etot << bshift) / N * 5 / 4) + 512;

    // workspace layout — ~45 MB
    unsigned char* h8 = (unsigned char*)d_ws;             // N*256 fp8 (transposed [n][c][hd])
    float* asrc   = (float*)(h8 + (size_t)N * 256);       // N*4
    float* adst   = asrc + (size_t)N * NH;                // N*4
    unsigned short* Wt    = (unsigned short*)(adst + (size_t)N * NH); // 256*128
    unsigned short* Wt2   = Wt + 256 * DIN;               // 256*64
    unsigned short* Wast1 = Wt2 + 256 * DHID;             // 16*128
    unsigned short* Wast2 = Wast1 + 16 * DIN;             // 16*64
    float* scl1   = (float*)(Wast2 + 16 * DHID);          // 64
    float* shf1   = scl1 + DHID;                          // 64
    float* scl2   = shf1 + DHID;                          // 64 (BN2 fold, fused pool)
    float* shf2   = scl2 + DHID;                          // 64
    float* sclX   = shf2 + DHID;                          // 128 (input-BN scale)
    float* shfX   = sclX + DIN;                           // 128 (input-BN shift)
    float* outacc = shfX + DIN;                           // N*64 (A2 alias space)
    unsigned short* A2 = (unsigned short*)outacc;         // alias: N*64 bf16 (layer-1 agg out)
    int*   deg    = (int*)(outacc + (size_t)N * DHID);    // N
    int*   rowptr = deg + N;                              // N+1
    int*   cursor = rowptr + N + 1;                       // N
    int*   col    = cursor + N;                           // E+N
    float* pool   = (float*)(col + Etot);                 // G*64
    float* cnt    = pool + (size_t)G * DHID;              // G
    int*   bsum   = (int*)(cnt + G);                      // <=256
    int*   bcur   = (int*)(((size_t)(bsum + 256) + 63) & ~(size_t)63); // NBUCK*BSTR (line-padded)
    unsigned long long* arena =
        (unsigned long long*)(((size_t)(bcur + NBUCK * BSTR) + 7) & ~(size_t)7); // NBUCK*cap*8B

    const int npool = G * DHID + G;
    const int nScanBlk = (N + 255) / 256;
    dim3 b256(256);

    // ---- fused init + weight prep (BN1 + BN2 + inputBN folds)
    int setupTot = N;
    if (setupTot < npool) setupTot = npool;
    if (setupTot < 256 * DIN) setupTot = 256 * DIN;
    k_setup<<<(setupTot + 255) / 256, b256, 0, stream>>>(
        deg, pool, bcur, N, npool,
        ing, inb, inm, inv, W1, W2, as1, ad1, as2, ad2,
        b1, bn1g, bn1b, bn1m, bn1v,
        b2, bn2g, bn2b, bn2m, bn2v,
        Wt, Wt2, Wast1, Wast2, scl1, shf1, scl2, shf2, sclX, shfX);

    // ---- CSR build (E real edges + N self-loops; cnt histogram in the self-loop tail)
    k_part<<<(Etot + EPB - 1) / EPB, b256, 0, stream>>>(ei, E, N, bshift, arena, bcur, deg, cap,
                                                        batch, cnt);
    k_scan_a<<<nScanBlk, b256, 0, stream>>>(deg, rowptr, bsum, N);
    k_scan_c2<<<nScanBlk, b256, 0, stream>>>(rowptr, cursor, bsum, N, Etot, nScanBlk);
    {
        dim3 gFill(NBUCK, (cap + 255) / 256);
        k_fill2<<<gFill, b256, 0, stream>>>(arena, bcur, cap, cursor, col);
    }

    // ---- layer 1 (MFMA, fused input-BN + fused att); agg writes bf16 A2 (bias+BN1+ReLU fused)
    k_gemm1<<<(N + GM - 1) / GM, b256, 0, stream>>>(x, sclX, shfX, Wt, Wast1, h8, asrc, adst, N);
    k_agg<<<(N + 3) / 4, b256, 0, stream>>>(rowptr, col, asrc, adst, h8,
                                            (float*)nullptr, A2, (const int*)nullptr,
                                            scl1, shf1, 1, N);

    // ---- layer 2 (MFMA, fused att); agg fuses BN2+ReLU+mean-pool atomics
    k_gemm2<<<(N + GM - 1) / GM, b256, 0, stream>>>(A2, Wt2, Wast2, h8, asrc, adst, N);
    k_agg<<<(N + 3) / 4, b256, 0, stream>>>(rowptr, col, asrc, adst, h8,
                                            pool, (unsigned short*)nullptr, batch,
                                            scl2, shf2, 0, N);

    // ---- head
    k_head<<<G, 64, 0, stream>>>(pool, cnt, fc1w, fc1b, fc2w, fc2b, (float*)d_out);
}

// Round 7
// 370.364 us; speedup vs baseline: 1.4113x; 1.4113x over previous
//
#include <hip/hip_runtime.h>
#include <hip/hip_bf16.h>

#define EPS   1e-5f
#define NH    4      // heads
#define DIN   128
#define DHID  64
#define DOUT  32
#define CAP   128    // per-wave LDS edge capacity in k_agg
#define GM    32     // rows per MFMA gemm block
#define NBUCK 64     // partition buckets (dst >> bshift)
#define BSTR  16     // bcur stride (ints) = one 64B line per bucket
#define EPT   16     // edges per thread in k_part
#define EPB   (256 * EPT)   // 4096 edges per k_part block

typedef __attribute__((ext_vector_type(8))) short short8;   // 8 bf16 (4 VGPRs)
typedef __attribute__((ext_vector_type(4))) float f32x4;    // MFMA accumulator
typedef __attribute__((ext_vector_type(2))) float f32x2;    // fp8 cvt result / packed fma

__device__ __forceinline__ float us2f(unsigned short u) {   // raw bf16 bits -> f32
    return __uint_as_float((unsigned)u << 16);
}
__device__ __forceinline__ unsigned short f2us(float v) {   // f32 -> bf16 bits (RN)
    __hip_bfloat16 hb = __float2bfloat16(v);
    return *(unsigned short*)&hb;
}
__device__ __forceinline__ unsigned char f2e4m3(float v) {  // f32 -> fp8 e4m3 (HW, OCP)
    int p = __builtin_amdgcn_cvt_pk_fp8_f32(v, 0.f, 0, false);
    return (unsigned char)(p & 0xff);
}
__device__ __forceinline__ float lrelu(float a) { return (a >= 0.f) ? a : 0.2f * a; }

// ---------------------------------------------------------------- fused init + weight prep
// deg preset to 1 (self-loop pre-counted); BN1/BN2/inputBN folded; group sizes via
// sorted-boundary writes (batch is sorted; unique writer per group; NO atomics).
__global__ __launch_bounds__(256) void k_setup(
    int* __restrict__ deg, float* __restrict__ pool, int* __restrict__ bcur,
    int N, int npool,
    const int* __restrict__ batch, int* __restrict__ gstart, int* __restrict__ gend,
    const float* __restrict__ ing, const float* __restrict__ inb,
    const float* __restrict__ inm, const float* __restrict__ inv,
    const float* __restrict__ W1, const float* __restrict__ W2,
    const float* __restrict__ as1, const float* __restrict__ ad1,
    const float* __restrict__ as2, const float* __restrict__ ad2,
    const float* __restrict__ b1,
    const float* __restrict__ bn1g, const float* __restrict__ bn1b,
    const float* __restrict__ bn1m, const float* __restrict__ bn1v,
    const float* __restrict__ b2,
    const float* __restrict__ bn2g, const float* __restrict__ bn2b,
    const float* __restrict__ bn2m, const float* __restrict__ bn2v,
    unsigned short* __restrict__ Wt, unsigned short* __restrict__ Wt2,
    unsigned short* __restrict__ Wast1, unsigned short* __restrict__ Wast2,
    float* __restrict__ scl1, float* __restrict__ shf1,
    float* __restrict__ scl2, float* __restrict__ shf2,
    float* __restrict__ sclX, float* __restrict__ shfX)
{
    int g = blockIdx.x * blockDim.x + threadIdx.x;
    if (g < N) {
        deg[g] = 1;                          // self-loop pre-counted
        int b = batch[g];                    // sorted: run boundaries have unique writers
        if (g == 0     || batch[g - 1] != b) gstart[b] = g;
        if (g == N - 1 || batch[g + 1] != b) gend[b]   = g + 1;
    }
    if (g < npool) pool[g] = 0.f;
    if (g < NBUCK * BSTR) bcur[g] = 0;
    if (g < 256 * DIN) {   // Wt[n][k] = W1[k][n]
        int n = g >> 7, k = g & 127;
        Wt[g] = f2us(W1[(size_t)k * 256 + n]);
    }
    if (g < 256 * DHID) {  // Wt2[n][k] = W2[k][n]
        int n = g >> 6, k = g & 63;
        Wt2[g] = f2us(W2[(size_t)k * 256 + n]);
    }
    if (g < 16 * DIN) {    // Wast1[c][k]: c<4 -> W1·as1 head c ; 4..7 -> W1·ad1 ; 8..15 -> 0
        int c = g >> 7, k = g & 127;
        float s = 0.f;
        if (c < 4)      { for (int j = 0; j < 64; ++j) s += W1[(size_t)k * 256 + c * 64 + j] * as1[c * 64 + j]; }
        else if (c < 8) { for (int j = 0; j < 64; ++j) s += W1[(size_t)k * 256 + (c - 4) * 64 + j] * ad1[(c - 4) * 64 + j]; }
        Wast1[g] = f2us(s);
    }
    if (g < 16 * DHID) {   // Wast2[c][k]
        int c = g >> 6, k = g & 63;
        float s = 0.f;
        if (c < 4)      { for (int j = 0; j < 64; ++j) s += W2[(size_t)k * 256 + c * 64 + j] * as2[c * 64 + j]; }
        else if (c < 8) { for (int j = 0; j < 64; ++j) s += W2[(size_t)k * 256 + (c - 4) * 64 + j] * ad2[(c - 4) * 64 + j]; }
        Wast2[g] = f2us(s);
    }
    if (g < DHID) {        // fold b1 + BN1 into scale/shift
        float sc = bn1g[g] * rsqrtf(bn1v[g] + EPS);
        scl1[g] = sc;
        shf1[g] = (b1[g] - bn1m[g]) * sc + bn1b[g];
        float sc2 = bn2g[g] * rsqrtf(bn2v[g] + EPS);   // fold b2 + BN2 (for fused pool)
        scl2[g] = sc2;
        shf2[g] = (b2[g] - bn2m[g]) * sc2 + bn2b[g];
    }
    if (g < DIN) {         // fold input BN into scale/shift (for k_gemm1)
        float sc = ing[g] * rsqrtf(inv[g] + EPS);
        sclX[g] = sc;
        shfX[g] = inb[g] - inm[g] * sc;
    }
}

// ---------------------------------------------------------------- scan phase A: per-block exclusive scan
__global__ __launch_bounds__(256) void k_scan_a(const int* __restrict__ deg,
                                                int* __restrict__ rowptr,
                                                int* __restrict__ bsum, int N) {
    __shared__ int sh[256];
    const int t = threadIdx.x;
    const int i = blockIdx.x * 256 + t;
    int v = (i < N) ? deg[i] : 0;
    sh[t] = v;
    __syncthreads();
    #pragma unroll
    for (int o = 1; o < 256; o <<= 1) {
        int u = (t >= o) ? sh[t - o] : 0;
        __syncthreads();
        sh[t] += u;
        __syncthreads();
    }
    if (i < N) rowptr[i] = sh[t] - v;
    if (t == 255) bsum[blockIdx.x] = sh[255];
}

// ---------------------------------------------------------------- scan phase B+C merged
__global__ __launch_bounds__(256) void k_scan_c2(int* __restrict__ rowptr,
                                                 int* __restrict__ cursor,
                                                 const int* __restrict__ bsum,
                                                 int N, int Etot, int nb) {
    __shared__ int sh[256];
    const int t = threadIdx.x;
    int v = (t < nb) ? bsum[t] : 0;
    sh[t] = v;
    __syncthreads();
    #pragma unroll
    for (int o = 1; o < 256; o <<= 1) {
        int u = (t >= o) ? sh[t - o] : 0;
        __syncthreads();
        sh[t] += u;
        __syncthreads();
    }
    const int off = (blockIdx.x > 0) ? sh[blockIdx.x - 1] : 0;
    const int i = blockIdx.x * 256 + t;
    if (i < N) {
        int r = rowptr[i] + off;
        rowptr[i] = r;
        cursor[i] = r;
    }
    if (i == 0) rowptr[N] = Etot;
}

// ---------------------------------------------------------------- CSR fill phase A: bucket partition + deg hist
// (round-5 form: NO cnt atomics here)
__global__ __launch_bounds__(256) void k_part(
    const int* __restrict__ ei, int E, int N, int bshift,
    unsigned long long* __restrict__ arena, int* __restrict__ bcur,
    int* __restrict__ deg, int cap)
{
    __shared__ int lhist[NBUCK];
    __shared__ int lbase[NBUCK];
    const int t = threadIdx.x;
    const int e0 = blockIdx.x * EPB;
    const int eEnd = min(e0 + EPB, E + N);

    if (t < NBUCK) lhist[t] = 0;
    __syncthreads();

    int myb[EPT], myd[EPT], mys[EPT];
    #pragma unroll
    for (int r = 0; r < EPT; ++r) {
        int e = e0 + r * 256 + t;
        myb[r] = -1;
        if (e < eEnd) {
            int s, d;
            if (e < E) { s = ei[e]; d = ei[E + e]; atomicAdd(&deg[d], 1); }
            else       { s = d = e - E; }          // self-loop: deg pre-set to 1 in setup
            int b = d >> bshift;
            myb[r] = b; myd[r] = d; mys[r] = s;
            atomicAdd(&lhist[b], 1);
        }
    }
    __syncthreads();

    if (t < NBUCK) {
        int c = lhist[t];
        lbase[t] = c ? atomicAdd(&bcur[t * BSTR], c) : 0;   // one line per bucket
        lhist[t] = 0;     // reuse as local bump
    }
    __syncthreads();

    #pragma unroll
    for (int r = 0; r < EPT; ++r) {
        int b = myb[r];
        if (b >= 0) {
            int li = atomicAdd(&lhist[b], 1);
            int pos = lbase[b] + li;
            if (pos >= cap) pos = cap - 1;    // safety (statistically unreachable)
            arena[(size_t)b * cap + pos] =
                ((unsigned long long)(unsigned)myd[r] << 32) | (unsigned)mys[r];
        }
    }
}

// ---------------------------------------------------------------- CSR fill phase B: bucket-local scatter
__global__ __launch_bounds__(256) void k_fill2(
    const unsigned long long* __restrict__ arena, const int* __restrict__ bcur,
    int cap, int* __restrict__ cursor, int* __restrict__ col)
{
    const int b = blockIdx.x;
    const int idx = blockIdx.y * 256 + threadIdx.x;
    if (idx >= bcur[b * BSTR]) return;
    unsigned long long v = arena[(size_t)b * cap + idx];
    int d = (int)(v >> 32);
    int s = (int)(v & 0xffffffffu);
    int pos = atomicAdd(&cursor[d], 1);
    col[pos] = s;
}

// ---------------------------------------------------------------- layer-1 GEMM via MFMA (input BN fused)
__global__ __launch_bounds__(256) void k_gemm1(
    const float* __restrict__ x,             // [N][128] f32
    const float* __restrict__ sclX, const float* __restrict__ shfX,
    const unsigned short* __restrict__ Wt,   // [256][128] bf16
    const unsigned short* __restrict__ Wast, // [16][128] bf16 (cols 8..15 zero)
    unsigned char* __restrict__ h,           // [N][256] fp8 (transposed [n][c][hd])
    float* __restrict__ asrc, float* __restrict__ adst, int N)
{
    __shared__ float Csh[GM][260];
    const int t = threadIdx.x;
    const int lane = t & 63, wv = t >> 6;
    const int qm = lane & 15, qd = lane >> 4;
    const int base = blockIdx.x * GM;

    short8 afr[2][4];
    #pragma unroll
    for (int ks = 0; ks < 4; ++ks) {
        const int k0 = qd * 8 + ks * 32;
        float4 s0 = *(const float4*)(sclX + k0), s1 = *(const float4*)(sclX + k0 + 4);
        float4 h0 = *(const float4*)(shfX + k0), h1 = *(const float4*)(shfX + k0 + 4);
        #pragma unroll
        for (int rt = 0; rt < 2; ++rt) {
            int node = base + rt * 16 + qm;
            if (node >= N) node = N - 1;
            const float* xp = x + (size_t)node * DIN + k0;
            float4 x0 = *(const float4*)xp, x1 = *(const float4*)(xp + 4);
            short8 v;
            v[0] = f2us(x0.x * s0.x + h0.x); v[1] = f2us(x0.y * s0.y + h0.y);
            v[2] = f2us(x0.z * s0.z + h0.z); v[3] = f2us(x0.w * s0.w + h0.w);
            v[4] = f2us(x1.x * s1.x + h1.x); v[5] = f2us(x1.y * s1.y + h1.y);
            v[6] = f2us(x1.z * s1.z + h1.z); v[7] = f2us(x1.w * s1.w + h1.w);
            afr[rt][ks] = v;
        }
    }

    const int n0 = wv * 64;
    f32x4 acc[2][4];
    #pragma unroll
    for (int rt = 0; rt < 2; ++rt)
        #pragma unroll
        for (int ct = 0; ct < 4; ++ct)
            acc[rt][ct] = (f32x4){0.f, 0.f, 0.f, 0.f};

    #pragma unroll
    for (int ct = 0; ct < 4; ++ct) {
        const unsigned short* bp = Wt + (size_t)(n0 + ct * 16 + qm) * DIN + qd * 8;
        #pragma unroll
        for (int ks = 0; ks < 4; ++ks) {
            short8 bfr = *(const short8*)(bp + ks * 32);
            acc[0][ct] = __builtin_amdgcn_mfma_f32_16x16x32_bf16(afr[0][ks], bfr, acc[0][ct], 0, 0, 0);
            acc[1][ct] = __builtin_amdgcn_mfma_f32_16x16x32_bf16(afr[1][ks], bfr, acc[1][ct], 0, 0, 0);
        }
    }

    // fused attention logits: [asrc|adst] = A @ Wast^T (reuses afr)
    {
        const unsigned short* wp = Wast + (size_t)qm * DIN + qd * 8;
        f32x4 aat[2];
        aat[0] = (f32x4){0.f, 0.f, 0.f, 0.f};
        aat[1] = (f32x4){0.f, 0.f, 0.f, 0.f};
        #pragma unroll
        for (int ks = 0; ks < 4; ++ks) {
            short8 wfr = *(const short8*)(wp + ks * 32);
            aat[0] = __builtin_amdgcn_mfma_f32_16x16x32_bf16(afr[0][ks], wfr, aat[0], 0, 0, 0);
            aat[1] = __builtin_amdgcn_mfma_f32_16x16x32_bf16(afr[1][ks], wfr, aat[1], 0, 0, 0);
        }
        const int c = qm;   // C layout: col = lane&15, row = qd*4+rg
        #pragma unroll
        for (int rt = 0; rt < 2; ++rt)
            #pragma unroll
            for (int rg = 0; rg < 4; ++rg) {
                int nd = base + rt * 16 + qd * 4 + rg;
                if (nd < N) {
                    if (c < 4)      asrc[nd * 4 + c] = aat[rt][rg];
                    else if (c < 8) adst[nd * 4 + (c - 4)] = aat[rt][rg];
                }
            }
    }

    #pragma unroll
    for (int rt = 0; rt < 2; ++rt)
        #pragma unroll
        for (int ct = 0; ct < 4; ++ct)
            #pragma unroll
            for (int rg = 0; rg < 4; ++rg)
                Csh[rt * 16 + qd * 4 + rg][n0 + ct * 16 + qm] = acc[rt][ct][rg];
    __syncthreads();

    const int hcol = ((t & 3) << 6) | (t >> 2);   // h[n][t] <- C[n][(t&3)*64 + (t>>2)]
    for (int r = 0; r < GM; ++r) {
        int node = base + r;
        if (node >= N) break;
        h[(size_t)node * 256 + t] = f2e4m3(Csh[r][hcol]);
    }
}

// ---------------------------------------------------------------- layer-2 GEMM via MFMA (K=64)
__global__ __launch_bounds__(256) void k_gemm2(
    const unsigned short* __restrict__ A2,   // [N][64] bf16
    const unsigned short* __restrict__ Wt2,  // [256][64] bf16
    const unsigned short* __restrict__ Wast, // [16][64] bf16
    unsigned char* __restrict__ h,
    float* __restrict__ asrc, float* __restrict__ adst, int N)
{
    __shared__ float Csh[GM][260];
    const int t = threadIdx.x;
    const int lane = t & 63, wv = t >> 6;
    const int qm = lane & 15, qd = lane >> 4;
    const int base = blockIdx.x * GM;

    short8 afr[2][2];
    #pragma unroll
    for (int rt = 0; rt < 2; ++rt) {
        int node = base + rt * 16 + qm;
        if (node >= N) node = N - 1;
        const unsigned short* ap = A2 + (size_t)node * DHID + qd * 8;
        #pragma unroll
        for (int ks = 0; ks < 2; ++ks)
            afr[rt][ks] = *(const short8*)(ap + ks * 32);
    }

    const int n0 = wv * 64;
    f32x4 acc[2][4];
    #pragma unroll
    for (int rt = 0; rt < 2; ++rt)
        #pragma unroll
        for (int ct = 0; ct < 4; ++ct)
            acc[rt][ct] = (f32x4){0.f, 0.f, 0.f, 0.f};

    #pragma unroll
    for (int ct = 0; ct < 4; ++ct) {
        const unsigned short* bp = Wt2 + (size_t)(n0 + ct * 16 + qm) * DHID + qd * 8;
        #pragma unroll
        for (int ks = 0; ks < 2; ++ks) {
            short8 bfr = *(const short8*)(bp + ks * 32);
            acc[0][ct] = __builtin_amdgcn_mfma_f32_16x16x32_bf16(afr[0][ks], bfr, acc[0][ct], 0, 0, 0);
            acc[1][ct] = __builtin_amdgcn_mfma_f32_16x16x32_bf16(afr[1][ks], bfr, acc[1][ct], 0, 0, 0);
        }
    }

    // fused attention logits
    {
        const unsigned short* wp = Wast + (size_t)qm * DHID + qd * 8;
        f32x4 aat[2];
        aat[0] = (f32x4){0.f, 0.f, 0.f, 0.f};
        aat[1] = (f32x4){0.f, 0.f, 0.f, 0.f};
        #pragma unroll
        for (int ks = 0; ks < 2; ++ks) {
            short8 wfr = *(const short8*)(wp + ks * 32);
            aat[0] = __builtin_amdgcn_mfma_f32_16x16x32_bf16(afr[0][ks], wfr, aat[0], 0, 0, 0);
            aat[1] = __builtin_amdgcn_mfma_f32_16x16x32_bf16(afr[1][ks], wfr, aat[1], 0, 0, 0);
        }
        const int c = qm;
        #pragma unroll
        for (int rt = 0; rt < 2; ++rt)
            #pragma unroll
            for (int rg = 0; rg < 4; ++rg) {
                int nd = base + rt * 16 + qd * 4 + rg;
                if (nd < N) {
                    if (c < 4)      asrc[nd * 4 + c] = aat[rt][rg];
                    else if (c < 8) adst[nd * 4 + (c - 4)] = aat[rt][rg];
                }
            }
    }

    #pragma unroll
    for (int rt = 0; rt < 2; ++rt)
        #pragma unroll
        for (int ct = 0; ct < 4; ++ct)
            #pragma unroll
            for (int rg = 0; rg < 4; ++rg)
                Csh[rt * 16 + qd * 4 + rg][n0 + ct * 16 + qm] = acc[rt][ct][rg];
    __syncthreads();

    const int hcol = ((t & 3) << 6) | (t >> 2);
    for (int r = 0; r < GM; ++r) {
        int node = base + r;
        if (node >= N) break;
        h[(size_t)node * 256 + t] = f2e4m3(Csh[r][hcol]);
    }
}

// ---------------------------------------------------------------- pull-style GAT aggregation (fp8 h)
// Pass B: lane = channel-dword; 4 independent 64-lane dword gathers per iteration;
// head-pair accumulation via packed f32x2 FMA.
// mode 1: write bf16 A2 (bias+BN1+ReLU). mode 0: fused pool — BN2+ReLU+atomicAdd to pool[batch[d]]
// (64 distinct lane addresses per wave -> no intra-wave conflict).
__global__ __launch_bounds__(256) void k_agg(
    const int* __restrict__ rowptr, const int* __restrict__ col,
    const float* __restrict__ asrc, const float* __restrict__ adst,
    const unsigned char* __restrict__ h8,
    float* __restrict__ pool, unsigned short* __restrict__ outb,
    const int* __restrict__ batch,
    const float* __restrict__ scl, const float* __restrict__ shf,
    int mode, int N)
{
    __shared__ float4 exs[4][CAP];
    __shared__ int    cols[4][CAP];
    const int lane = threadIdx.x & 63;
    const int wv   = threadIdx.x >> 6;
    const int d = (blockIdx.x << 2) + wv;
    if (d >= N) return;
    const int r0  = rowptr[d];
    const int deg = rowptr[d + 1] - r0;        // >= 1 (self-loop)

    const float4 ad4 = ((const float4*)adst)[d];
    const float4* __restrict__ as4 = (const float4*)asrc;

    // pass A: exp(lrelu(logit)) -> LDS, per-head sum
    float sm0 = 0.f, sm1 = 0.f, sm2 = 0.f, sm3 = 0.f;
    for (int j = lane; j < deg; j += 64) {
        int s = col[r0 + j];
        float4 a = as4[s];
        float e0 = __expf(lrelu(a.x + ad4.x));
        float e1 = __expf(lrelu(a.y + ad4.y));
        float e2 = __expf(lrelu(a.z + ad4.z));
        float e3 = __expf(lrelu(a.w + ad4.w));
        if (j < CAP) { cols[wv][j] = s; exs[wv][j] = make_float4(e0, e1, e2, e3); }
        sm0 += e0; sm1 += e1; sm2 += e2; sm3 += e3;
    }
    #pragma unroll
    for (int o = 1; o < 64; o <<= 1) {
        sm0 += __shfl_xor(sm0, o, 64);
        sm1 += __shfl_xor(sm1, o, 64);
        sm2 += __shfl_xor(sm2, o, 64);
        sm3 += __shfl_xor(sm3, o, 64);
    }
    const float i0 = 0.25f / sm0, i1 = 0.25f / sm1, i2 = 0.25f / sm2, i3 = 0.25f / sm3;

    // pass B: packed head-pair accumulation (2 chains for ILP)
    const unsigned int* __restrict__ hu = (const unsigned int*)h8;
    f32x2 accA01 = {0.f, 0.f}, accA23 = {0.f, 0.f};
    f32x2 accB01 = {0.f, 0.f}, accB23 = {0.f, 0.f};
    if (deg <= CAP) {
        int j = 0;
        for (; j + 3 < deg; j += 4) {
            int sA = cols[wv][j],     sB = cols[wv][j + 1];
            int sC = cols[wv][j + 2], sD = cols[wv][j + 3];
            unsigned int vA = hu[(size_t)sA * 64 + lane];
            unsigned int vB = hu[(size_t)sB * 64 + lane];
            unsigned int vC = hu[(size_t)sC * 64 + lane];
            unsigned int vD = hu[(size_t)sD * 64 + lane];
            float4 wA = exs[wv][j],     wB = exs[wv][j + 1];
            float4 wC = exs[wv][j + 2], wD = exs[wv][j + 3];
            f32x2 lA = __builtin_amdgcn_cvt_pk_f32_fp8(vA, false), hA = __builtin_amdgcn_cvt_pk_f32_fp8(vA, true);
            f32x2 lB = __builtin_amdgcn_cvt_pk_f32_fp8(vB, false), hB = __builtin_amdgcn_cvt_pk_f32_fp8(vB, true);
            f32x2 lC = __builtin_amdgcn_cvt_pk_f32_fp8(vC, false), hC = __builtin_amdgcn_cvt_pk_f32_fp8(vC, true);
            f32x2 lD = __builtin_amdgcn_cvt_pk_f32_fp8(vD, false), hD = __builtin_amdgcn_cvt_pk_f32_fp8(vD, true);
            accA01 += (f32x2){wA.x, wA.y} * lA; accA23 += (f32x2){wA.z, wA.w} * hA;
            accB01 += (f32x2){wB.x, wB.y} * lB; accB23 += (f32x2){wB.z, wB.w} * hB;
            accA01 += (f32x2){wC.x, wC.y} * lC; accA23 += (f32x2){wC.z, wC.w} * hC;
            accB01 += (f32x2){wD.x, wD.y} * lD; accB23 += (f32x2){wD.z, wD.w} * hD;
        }
        for (; j < deg; ++j) {
            int s = cols[wv][j];
            unsigned int v = hu[(size_t)s * 64 + lane];
            float4 w = exs[wv][j];
            f32x2 lo = __builtin_amdgcn_cvt_pk_f32_fp8(v, false), hi = __builtin_amdgcn_cvt_pk_f32_fp8(v, true);
            accA01 += (f32x2){w.x, w.y} * lo; accA23 += (f32x2){w.z, w.w} * hi;
        }
    } else {                                     // rare: deg > CAP, recompute weights
        for (int j = 0; j < deg; ++j) {
            int s; float4 w;
            if (j < CAP) { s = cols[wv][j]; w = exs[wv][j]; }
            else {
                s = col[r0 + j];
                float4 a = as4[s];
                w.x = __expf(lrelu(a.x + ad4.x)); w.y = __expf(lrelu(a.y + ad4.y));
                w.z = __expf(lrelu(a.z + ad4.z)); w.w = __expf(lrelu(a.w + ad4.w));
            }
            unsigned int v = hu[(size_t)s * 64 + lane];
            f32x2 lo = __builtin_amdgcn_cvt_pk_f32_fp8(v, false), hi = __builtin_amdgcn_cvt_pk_f32_fp8(v, true);
            accA01 += (f32x2){w.x, w.y} * lo; accA23 += (f32x2){w.z, w.w} * hi;
        }
    }
    f32x2 s01 = accA01 + accB01;
    f32x2 s23 = accA23 + accB23;
    float acc = s01.x * i0 + s01.y * i1 + s23.x * i2 + s23.y * i3;

    if (mode) {
        float v = fmaxf(acc * scl[lane] + shf[lane], 0.f);
        outb[(size_t)d * 64 + lane] = f2us(v);
    } else {
        // fused global-mean-pool: BN2 + ReLU + atomic accumulate per graph
        int gr = batch[d];
        float v = fmaxf(acc * scl[lane] + shf[lane], 0.f);
        atomicAdd(&pool[(size_t)gr * 64 + lane], v);
    }
}

// ---------------------------------------------------------------- head
__global__ void k_head(const float* __restrict__ pool,
                       const int* __restrict__ gstart, const int* __restrict__ gend,
                       const float* __restrict__ fc1w, const float* __restrict__ fc1b,
                       const float* __restrict__ fc2w, const float* __restrict__ fc2b,
                       float* __restrict__ out)
{
    int g = blockIdx.x;
    int t = threadIdx.x;  // 64 threads
    __shared__ float emb[64];
    __shared__ float z1[32];
    float c = fmaxf((float)(gend[g] - gstart[g]), 1.0f);   // empty groups: pool row is 0 -> emb 0
    emb[t] = pool[g * 64 + t] / c;
    __syncthreads();
    if (t < 32) {
        float s = fc1b[t];
        for (int k = 0; k < 64; ++k) s += emb[k] * fc1w[k * 32 + t];
        z1[t] = fmaxf(s, 0.f);
    }
    __syncthreads();
    if (t < 32) {
        float o = fc2b[t];
        for (int j = 0; j < 32; ++j) o += z1[j] * fc2w[j * 32 + t];
        out[g * 32 + t] = o;
    }
}

// ---------------------------------------------------------------- launch
extern "C" void kernel_launch(void* const* d_in, const int* in_sizes, int n_in,
                              void* d_out, int out_size, void* d_ws, size_t ws_size,
                              hipStream_t stream)
{
    const float* x    = (const float*)d_in[0];
    const int*   ei   = (const int*)d_in[1];
    const int*   batch= (const int*)d_in[2];
    const float* ing  = (const float*)d_in[3];
    const float* inb  = (const float*)d_in[4];
    const float* inm  = (const float*)d_in[5];
    const float* inv  = (const float*)d_in[6];
    const float* W1   = (const float*)d_in[7];
    const float* as1  = (const float*)d_in[8];
    const float* ad1  = (const float*)d_in[9];
    const float* b1   = (const float*)d_in[10];
    const float* bn1g = (const float*)d_in[11];
    const float* bn1b = (const float*)d_in[12];
    const float* bn1m = (const float*)d_in[13];
    const float* bn1v = (const float*)d_in[14];
    const float* W2   = (const float*)d_in[15];
    const float* as2  = (const float*)d_in[16];
    const float* ad2  = (const float*)d_in[17];
    const float* b2   = (const float*)d_in[18];
    const float* bn2g = (const float*)d_in[19];
    const float* bn2b = (const float*)d_in[20];
    const float* bn2m = (const float*)d_in[21];
    const float* bn2v = (const float*)d_in[22];
    const float* fc1w = (const float*)d_in[23];
    const float* fc1b = (const float*)d_in[24];
    const float* fc2w = (const float*)d_in[25];
    const float* fc2b = (const float*)d_in[26];

    const int N = in_sizes[0] / DIN;
    const int E = in_sizes[1] / 2;
    const int G = out_size / DOUT;
    const int Etot = E + N;

    // bucket shift: smallest with (N-1)>>bshift < NBUCK
    int bshift = 0;
    while ((N >> bshift) >= NBUCK) ++bshift;
    // per-bucket arena capacity: expected density * 1.25 + slack
    const int cap = (int)(((long long)Etot << bshift) / N * 5 / 4) + 512;

    // workspace layout — ~45 MB
    unsigned char* h8 = (unsigned char*)d_ws;             // N*256 fp8 (transposed [n][c][hd])
    float* asrc   = (float*)(h8 + (size_t)N * 256);       // N*4
    float* adst   = asrc + (size_t)N * NH;                // N*4
    unsigned short* Wt    = (unsigned short*)(adst + (size_t)N * NH); // 256*128
    unsigned short* Wt2   = Wt + 256 * DIN;               // 256*64
    unsigned short* Wast1 = Wt2 + 256 * DHID;             // 16*128
    unsigned short* Wast2 = Wast1 + 16 * DIN;             // 16*64
    float* scl1   = (float*)(Wast2 + 16 * DHID);          // 64
    float* shf1   = scl1 + DHID;                          // 64
    float* scl2   = shf1 + DHID;                          // 64 (BN2 fold, fused pool)
    float* shf2   = scl2 + DHID;                          // 64
    float* sclX   = shf2 + DHID;                          // 128 (input-BN scale)
    float* shfX   = sclX + DIN;                           // 128 (input-BN shift)
    float* outacc = shfX + DIN;                           // N*64 (A2 alias space)
    unsigned short* A2 = (unsigned short*)outacc;         // alias: N*64 bf16 (layer-1 agg out)
    int*   deg    = (int*)(outacc + (size_t)N * DHID);    // N
    int*   rowptr = deg + N;                              // N+1
    int*   cursor = rowptr + N + 1;                       // N
    int*   col    = cursor + N;                           // E+N
    float* pool   = (float*)(col + Etot);                 // G*64
    int*   gstart = (int*)(pool + (size_t)G * DHID);      // G (group run start)
    int*   gend   = gstart + G;                           // G (group run end)
    int*   bsum   = gend + G;                             // <=256
    int*   bcur   = (int*)(((size_t)(bsum + 256) + 63) & ~(size_t)63); // NBUCK*BSTR (line-padded)
    unsigned long long* arena =
        (unsigned long long*)(((size_t)(bcur + NBUCK * BSTR) + 7) & ~(size_t)7); // NBUCK*cap*8B

    const int npool = G * DHID;
    const int nScanBlk = (N + 255) / 256;
    dim3 b256(256);

    // ---- fused init + weight prep (BN folds + sorted-boundary group counts)
    int setupTot = N;
    if (setupTot < npool) setupTot = npool;
    if (setupTot < 256 * DIN) setupTot = 256 * DIN;
    k_setup<<<(setupTot + 255) / 256, b256, 0, stream>>>(
        deg, pool, bcur, N, npool,
        batch, gstart, gend,
        ing, inb, inm, inv, W1, W2, as1, ad1, as2, ad2,
        b1, bn1g, bn1b, bn1m, bn1v,
        b2, bn2g, bn2b, bn2m, bn2v,
        Wt, Wt2, Wast1, Wast2, scl1, shf1, scl2, shf2, sclX, shfX);

    // ---- CSR build (E real edges + N self-loops)
    k_part<<<(Etot + EPB - 1) / EPB, b256, 0, stream>>>(ei, E, N, bshift, arena, bcur, deg, cap);
    k_scan_a<<<nScanBlk, b256, 0, stream>>>(deg, rowptr, bsum, N);
    k_scan_c2<<<nScanBlk, b256, 0, stream>>>(rowptr, cursor, bsum, N, Etot, nScanBlk);
    {
        dim3 gFill(NBUCK, (cap + 255) / 256);
        k_fill2<<<gFill, b256, 0, stream>>>(arena, bcur, cap, cursor, col);
    }

    // ---- layer 1 (MFMA, fused input-BN + fused att); agg writes bf16 A2 (bias+BN1+ReLU fused)
    k_gemm1<<<(N + GM - 1) / GM, b256, 0, stream>>>(x, sclX, shfX, Wt, Wast1, h8, asrc, adst, N);
    k_agg<<<(N + 3) / 4, b256, 0, stream>>>(rowptr, col, asrc, adst, h8,
                                            (float*)nullptr, A2, (const int*)nullptr,
                                            scl1, shf1, 1, N);

    // ---- layer 2 (MFMA, fused att); agg fuses BN2+ReLU+mean-pool atomics
    k_gemm2<<<(N + GM - 1) / GM, b256, 0, stream>>>(A2, Wt2, Wast2, h8, asrc, adst, N);
    k_agg<<<(N + 3) / 4, b256, 0, stream>>>(rowptr, col, asrc, adst, h8,
                                            pool, (unsigned short*)nullptr, batch,
                                            scl2, shf2, 0, N);

    // ---- head
    k_head<<<G, 64, 0, stream>>>(pool, gstart, gend, fc1w, fc1b, fc2w, fc2b, (float*)d_out);
}

// Round 8
// 359.302 us; speedup vs baseline: 1.4548x; 1.0308x over previous
//
#include <hip/hip_runtime.h>
#include <hip/hip_bf16.h>

#define EPS   1e-5f
#define NH    4      // heads
#define DIN   128
#define DHID  64
#define DOUT  32
#define PNODES 256   // nodes per k_pool block
#define CAP   128    // per-wave LDS edge capacity in k_agg
#define GM    32     // rows per MFMA gemm block
#define NBUCK 64     // partition buckets (dst >> bshift)
#define BSTR  16     // bcur stride (ints) = one 64B line per bucket
#define EPT   16     // edges per thread in k_part
#define EPB   (256 * EPT)   // 4096 edges per k_part block

typedef __attribute__((ext_vector_type(8))) short short8;   // 8 bf16 (4 VGPRs)
typedef __attribute__((ext_vector_type(4))) float f32x4;    // MFMA accumulator
typedef __attribute__((ext_vector_type(2))) float f32x2;    // fp8 cvt result / packed fma

__device__ __forceinline__ float us2f(unsigned short u) {   // raw bf16 bits -> f32
    return __uint_as_float((unsigned)u << 16);
}
__device__ __forceinline__ unsigned short f2us(float v) {   // f32 -> bf16 bits (RN)
    __hip_bfloat16 hb = __float2bfloat16(v);
    return *(unsigned short*)&hb;
}
__device__ __forceinline__ unsigned char f2e4m3(float v) {  // f32 -> fp8 e4m3 (HW, OCP)
    int p = __builtin_amdgcn_cvt_pk_fp8_f32(v, 0.f, 0, false);
    return (unsigned char)(p & 0xff);
}
__device__ __forceinline__ float lrelu(float a) { return (a >= 0.f) ? a : 0.2f * a; }

// ---------------------------------------------------------------- fused init + weight prep
// deg preset to 1 (self-loop pre-counted); BN1/BN2/inputBN folded; group sizes via
// sorted-boundary writes (batch is sorted; unique writer per group; NO atomics).
__global__ __launch_bounds__(256) void k_setup(
    int* __restrict__ deg, float* __restrict__ pool, int* __restrict__ bcur,
    int N, int npool,
    const int* __restrict__ batch, int* __restrict__ gstart, int* __restrict__ gend,
    const float* __restrict__ ing, const float* __restrict__ inb,
    const float* __restrict__ inm, const float* __restrict__ inv,
    const float* __restrict__ W1, const float* __restrict__ W2,
    const float* __restrict__ as1, const float* __restrict__ ad1,
    const float* __restrict__ as2, const float* __restrict__ ad2,
    const float* __restrict__ b1,
    const float* __restrict__ bn1g, const float* __restrict__ bn1b,
    const float* __restrict__ bn1m, const float* __restrict__ bn1v,
    const float* __restrict__ b2,
    const float* __restrict__ bn2g, const float* __restrict__ bn2b,
    const float* __restrict__ bn2m, const float* __restrict__ bn2v,
    unsigned short* __restrict__ Wt, unsigned short* __restrict__ Wt2,
    unsigned short* __restrict__ Wast1, unsigned short* __restrict__ Wast2,
    float* __restrict__ scl1, float* __restrict__ shf1,
    float* __restrict__ scl2, float* __restrict__ shf2,
    float* __restrict__ sclX, float* __restrict__ shfX)
{
    int g = blockIdx.x * blockDim.x + threadIdx.x;
    if (g < N) {
        deg[g] = 1;                          // self-loop pre-counted
        int b = batch[g];                    // sorted: run boundaries have unique writers
        if (g == 0     || batch[g - 1] != b) gstart[b] = g;
        if (g == N - 1 || batch[g + 1] != b) gend[b]   = g + 1;
    }
    if (g < npool) pool[g] = 0.f;
    if (g < NBUCK * BSTR) bcur[g] = 0;
    if (g < 256 * DIN) {   // Wt[n][k] = W1[k][n]
        int n = g >> 7, k = g & 127;
        Wt[g] = f2us(W1[(size_t)k * 256 + n]);
    }
    if (g < 256 * DHID) {  // Wt2[n][k] = W2[k][n]
        int n = g >> 6, k = g & 63;
        Wt2[g] = f2us(W2[(size_t)k * 256 + n]);
    }
    if (g < 16 * DIN) {    // Wast1[c][k]: c<4 -> W1·as1 head c ; 4..7 -> W1·ad1 ; 8..15 -> 0
        int c = g >> 7, k = g & 127;
        float s = 0.f;
        if (c < 4)      { for (int j = 0; j < 64; ++j) s += W1[(size_t)k * 256 + c * 64 + j] * as1[c * 64 + j]; }
        else if (c < 8) { for (int j = 0; j < 64; ++j) s += W1[(size_t)k * 256 + (c - 4) * 64 + j] * ad1[(c - 4) * 64 + j]; }
        Wast1[g] = f2us(s);
    }
    if (g < 16 * DHID) {   // Wast2[c][k]
        int c = g >> 6, k = g & 63;
        float s = 0.f;
        if (c < 4)      { for (int j = 0; j < 64; ++j) s += W2[(size_t)k * 256 + c * 64 + j] * as2[c * 64 + j]; }
        else if (c < 8) { for (int j = 0; j < 64; ++j) s += W2[(size_t)k * 256 + (c - 4) * 64 + j] * ad2[(c - 4) * 64 + j]; }
        Wast2[g] = f2us(s);
    }
    if (g < DHID) {        // fold b1 + BN1 into scale/shift
        float sc = bn1g[g] * rsqrtf(bn1v[g] + EPS);
        scl1[g] = sc;
        shf1[g] = (b1[g] - bn1m[g]) * sc + bn1b[g];
        float sc2 = bn2g[g] * rsqrtf(bn2v[g] + EPS);   // fold b2 + BN2 (for k_pool)
        scl2[g] = sc2;
        shf2[g] = (b2[g] - bn2m[g]) * sc2 + bn2b[g];
    }
    if (g < DIN) {         // fold input BN into scale/shift (for k_gemm1)
        float sc = ing[g] * rsqrtf(inv[g] + EPS);
        sclX[g] = sc;
        shfX[g] = inb[g] - inm[g] * sc;
    }
}

// ---------------------------------------------------------------- scan phase A: per-block exclusive scan
__global__ __launch_bounds__(256) void k_scan_a(const int* __restrict__ deg,
                                                int* __restrict__ rowptr,
                                                int* __restrict__ bsum, int N) {
    __shared__ int sh[256];
    const int t = threadIdx.x;
    const int i = blockIdx.x * 256 + t;
    int v = (i < N) ? deg[i] : 0;
    sh[t] = v;
    __syncthreads();
    #pragma unroll
    for (int o = 1; o < 256; o <<= 1) {
        int u = (t >= o) ? sh[t - o] : 0;
        __syncthreads();
        sh[t] += u;
        __syncthreads();
    }
    if (i < N) rowptr[i] = sh[t] - v;
    if (t == 255) bsum[blockIdx.x] = sh[255];
}

// ---------------------------------------------------------------- scan phase B+C merged
__global__ __launch_bounds__(256) void k_scan_c2(int* __restrict__ rowptr,
                                                 int* __restrict__ cursor,
                                                 const int* __restrict__ bsum,
                                                 int N, int Etot, int nb) {
    __shared__ int sh[256];
    const int t = threadIdx.x;
    int v = (t < nb) ? bsum[t] : 0;
    sh[t] = v;
    __syncthreads();
    #pragma unroll
    for (int o = 1; o < 256; o <<= 1) {
        int u = (t >= o) ? sh[t - o] : 0;
        __syncthreads();
        sh[t] += u;
        __syncthreads();
    }
    const int off = (blockIdx.x > 0) ? sh[blockIdx.x - 1] : 0;
    const int i = blockIdx.x * 256 + t;
    if (i < N) {
        int r = rowptr[i] + off;
        rowptr[i] = r;
        cursor[i] = r;
    }
    if (i == 0) rowptr[N] = Etot;
}

// ---------------------------------------------------------------- CSR fill phase A: bucket partition + deg hist
__global__ __launch_bounds__(256) void k_part(
    const int* __restrict__ ei, int E, int N, int bshift,
    unsigned long long* __restrict__ arena, int* __restrict__ bcur,
    int* __restrict__ deg, int cap)
{
    __shared__ int lhist[NBUCK];
    __shared__ int lbase[NBUCK];
    const int t = threadIdx.x;
    const int e0 = blockIdx.x * EPB;
    const int eEnd = min(e0 + EPB, E + N);

    if (t < NBUCK) lhist[t] = 0;
    __syncthreads();

    int myb[EPT], myd[EPT], mys[EPT];
    #pragma unroll
    for (int r = 0; r < EPT; ++r) {
        int e = e0 + r * 256 + t;
        myb[r] = -1;
        if (e < eEnd) {
            int s, d;
            if (e < E) { s = ei[e]; d = ei[E + e]; atomicAdd(&deg[d], 1); }
            else       { s = d = e - E; }          // self-loop: deg pre-set to 1 in setup
            int b = d >> bshift;
            myb[r] = b; myd[r] = d; mys[r] = s;
            atomicAdd(&lhist[b], 1);
        }
    }
    __syncthreads();

    if (t < NBUCK) {
        int c = lhist[t];
        lbase[t] = c ? atomicAdd(&bcur[t * BSTR], c) : 0;   // one line per bucket
        lhist[t] = 0;     // reuse as local bump
    }
    __syncthreads();

    #pragma unroll
    for (int r = 0; r < EPT; ++r) {
        int b = myb[r];
        if (b >= 0) {
            int li = atomicAdd(&lhist[b], 1);
            int pos = lbase[b] + li;
            if (pos >= cap) pos = cap - 1;    // safety (statistically unreachable)
            arena[(size_t)b * cap + pos] =
                ((unsigned long long)(unsigned)myd[r] << 32) | (unsigned)mys[r];
        }
    }
}

// ---------------------------------------------------------------- CSR fill phase B: bucket-local scatter
__global__ __launch_bounds__(256) void k_fill2(
    const unsigned long long* __restrict__ arena, const int* __restrict__ bcur,
    int cap, int* __restrict__ cursor, int* __restrict__ col)
{
    const int b = blockIdx.x;
    const int idx = blockIdx.y * 256 + threadIdx.x;
    if (idx >= bcur[b * BSTR]) return;
    unsigned long long v = arena[(size_t)b * cap + idx];
    int d = (int)(v >> 32);
    int s = (int)(v & 0xffffffffu);
    int pos = atomicAdd(&cursor[d], 1);
    col[pos] = s;
}

// ---------------------------------------------------------------- layer-1 GEMM via MFMA (input BN fused)
__global__ __launch_bounds__(256) void k_gemm1(
    const float* __restrict__ x,             // [N][128] f32
    const float* __restrict__ sclX, const float* __restrict__ shfX,
    const unsigned short* __restrict__ Wt,   // [256][128] bf16
    const unsigned short* __restrict__ Wast, // [16][128] bf16 (cols 8..15 zero)
    unsigned char* __restrict__ h,           // [N][256] fp8 (transposed [n][c][hd])
    float* __restrict__ asrc, float* __restrict__ adst, int N)
{
    __shared__ float Csh[GM][260];
    const int t = threadIdx.x;
    const int lane = t & 63, wv = t >> 6;
    const int qm = lane & 15, qd = lane >> 4;
    const int base = blockIdx.x * GM;

    short8 afr[2][4];
    #pragma unroll
    for (int ks = 0; ks < 4; ++ks) {
        const int k0 = qd * 8 + ks * 32;
        float4 s0 = *(const float4*)(sclX + k0), s1 = *(const float4*)(sclX + k0 + 4);
        float4 h0 = *(const float4*)(shfX + k0), h1 = *(const float4*)(shfX + k0 + 4);
        #pragma unroll
        for (int rt = 0; rt < 2; ++rt) {
            int node = base + rt * 16 + qm;
            if (node >= N) node = N - 1;
            const float* xp = x + (size_t)node * DIN + k0;
            float4 x0 = *(const float4*)xp, x1 = *(const float4*)(xp + 4);
            short8 v;
            v[0] = f2us(x0.x * s0.x + h0.x); v[1] = f2us(x0.y * s0.y + h0.y);
            v[2] = f2us(x0.z * s0.z + h0.z); v[3] = f2us(x0.w * s0.w + h0.w);
            v[4] = f2us(x1.x * s1.x + h1.x); v[5] = f2us(x1.y * s1.y + h1.y);
            v[6] = f2us(x1.z * s1.z + h1.z); v[7] = f2us(x1.w * s1.w + h1.w);
            afr[rt][ks] = v;
        }
    }

    const int n0 = wv * 64;
    f32x4 acc[2][4];
    #pragma unroll
    for (int rt = 0; rt < 2; ++rt)
        #pragma unroll
        for (int ct = 0; ct < 4; ++ct)
            acc[rt][ct] = (f32x4){0.f, 0.f, 0.f, 0.f};

    #pragma unroll
    for (int ct = 0; ct < 4; ++ct) {
        const unsigned short* bp = Wt + (size_t)(n0 + ct * 16 + qm) * DIN + qd * 8;
        #pragma unroll
        for (int ks = 0; ks < 4; ++ks) {
            short8 bfr = *(const short8*)(bp + ks * 32);
            acc[0][ct] = __builtin_amdgcn_mfma_f32_16x16x32_bf16(afr[0][ks], bfr, acc[0][ct], 0, 0, 0);
            acc[1][ct] = __builtin_amdgcn_mfma_f32_16x16x32_bf16(afr[1][ks], bfr, acc[1][ct], 0, 0, 0);
        }
    }

    // fused attention logits: [asrc|adst] = A @ Wast^T (reuses afr)
    {
        const unsigned short* wp = Wast + (size_t)qm * DIN + qd * 8;
        f32x4 aat[2];
        aat[0] = (f32x4){0.f, 0.f, 0.f, 0.f};
        aat[1] = (f32x4){0.f, 0.f, 0.f, 0.f};
        #pragma unroll
        for (int ks = 0; ks < 4; ++ks) {
            short8 wfr = *(const short8*)(wp + ks * 32);
            aat[0] = __builtin_amdgcn_mfma_f32_16x16x32_bf16(afr[0][ks], wfr, aat[0], 0, 0, 0);
            aat[1] = __builtin_amdgcn_mfma_f32_16x16x32_bf16(afr[1][ks], wfr, aat[1], 0, 0, 0);
        }
        const int c = qm;   // C layout: col = lane&15, row = qd*4+rg
        #pragma unroll
        for (int rt = 0; rt < 2; ++rt)
            #pragma unroll
            for (int rg = 0; rg < 4; ++rg) {
                int nd = base + rt * 16 + qd * 4 + rg;
                if (nd < N) {
                    if (c < 4)      asrc[nd * 4 + c] = aat[rt][rg];
                    else if (c < 8) adst[nd * 4 + (c - 4)] = aat[rt][rg];
                }
            }
    }

    #pragma unroll
    for (int rt = 0; rt < 2; ++rt)
        #pragma unroll
        for (int ct = 0; ct < 4; ++ct)
            #pragma unroll
            for (int rg = 0; rg < 4; ++rg)
                Csh[rt * 16 + qd * 4 + rg][n0 + ct * 16 + qm] = acc[rt][ct][rg];
    __syncthreads();

    const int hcol = ((t & 3) << 6) | (t >> 2);   // h[n][t] <- C[n][(t&3)*64 + (t>>2)]
    for (int r = 0; r < GM; ++r) {
        int node = base + r;
        if (node >= N) break;
        h[(size_t)node * 256 + t] = f2e4m3(Csh[r][hcol]);
    }
}

// ---------------------------------------------------------------- layer-2 GEMM via MFMA (K=64)
__global__ __launch_bounds__(256) void k_gemm2(
    const unsigned short* __restrict__ A2,   // [N][64] bf16
    const unsigned short* __restrict__ Wt2,  // [256][64] bf16
    const unsigned short* __restrict__ Wast, // [16][64] bf16
    unsigned char* __restrict__ h,
    float* __restrict__ asrc, float* __restrict__ adst, int N)
{
    __shared__ float Csh[GM][260];
    const int t = threadIdx.x;
    const int lane = t & 63, wv = t >> 6;
    const int qm = lane & 15, qd = lane >> 4;
    const int base = blockIdx.x * GM;

    short8 afr[2][2];
    #pragma unroll
    for (int rt = 0; rt < 2; ++rt) {
        int node = base + rt * 16 + qm;
        if (node >= N) node = N - 1;
        const unsigned short* ap = A2 + (size_t)node * DHID + qd * 8;
        #pragma unroll
        for (int ks = 0; ks < 2; ++ks)
            afr[rt][ks] = *(const short8*)(ap + ks * 32);
    }

    const int n0 = wv * 64;
    f32x4 acc[2][4];
    #pragma unroll
    for (int rt = 0; rt < 2; ++rt)
        #pragma unroll
        for (int ct = 0; ct < 4; ++ct)
            acc[rt][ct] = (f32x4){0.f, 0.f, 0.f, 0.f};

    #pragma unroll
    for (int ct = 0; ct < 4; ++ct) {
        const unsigned short* bp = Wt2 + (size_t)(n0 + ct * 16 + qm) * DHID + qd * 8;
        #pragma unroll
        for (int ks = 0; ks < 2; ++ks) {
            short8 bfr = *(const short8*)(bp + ks * 32);
            acc[0][ct] = __builtin_amdgcn_mfma_f32_16x16x32_bf16(afr[0][ks], bfr, acc[0][ct], 0, 0, 0);
            acc[1][ct] = __builtin_amdgcn_mfma_f32_16x16x32_bf16(afr[1][ks], bfr, acc[1][ct], 0, 0, 0);
        }
    }

    // fused attention logits
    {
        const unsigned short* wp = Wast + (size_t)qm * DHID + qd * 8;
        f32x4 aat[2];
        aat[0] = (f32x4){0.f, 0.f, 0.f, 0.f};
        aat[1] = (f32x4){0.f, 0.f, 0.f, 0.f};
        #pragma unroll
        for (int ks = 0; ks < 2; ++ks) {
            short8 wfr = *(const short8*)(wp + ks * 32);
            aat[0] = __builtin_amdgcn_mfma_f32_16x16x32_bf16(afr[0][ks], wfr, aat[0], 0, 0, 0);
            aat[1] = __builtin_amdgcn_mfma_f32_16x16x32_bf16(afr[1][ks], wfr, aat[1], 0, 0, 0);
        }
        const int c = qm;
        #pragma unroll
        for (int rt = 0; rt < 2; ++rt)
            #pragma unroll
            for (int rg = 0; rg < 4; ++rg) {
                int nd = base + rt * 16 + qd * 4 + rg;
                if (nd < N) {
                    if (c < 4)      asrc[nd * 4 + c] = aat[rt][rg];
                    else if (c < 8) adst[nd * 4 + (c - 4)] = aat[rt][rg];
                }
            }
    }

    #pragma unroll
    for (int rt = 0; rt < 2; ++rt)
        #pragma unroll
        for (int ct = 0; ct < 4; ++ct)
            #pragma unroll
            for (int rg = 0; rg < 4; ++rg)
                Csh[rt * 16 + qd * 4 + rg][n0 + ct * 16 + qm] = acc[rt][ct][rg];
    __syncthreads();

    const int hcol = ((t & 3) << 6) | (t >> 2);
    for (int r = 0; r < GM; ++r) {
        int node = base + r;
        if (node >= N) break;
        h[(size_t)node * 256 + t] = f2e4m3(Csh[r][hcol]);
    }
}

// ---------------------------------------------------------------- pull-style GAT aggregation (fp8 h)
// Pass B: lane = channel-dword; 4 independent 64-lane dword gathers per iteration;
// head-pair accumulation via packed f32x2 FMA.
// mode 1: write bf16 A2 (bias+BN1+ReLU). mode 0: plain coalesced f32 outacc write.
__global__ __launch_bounds__(256) void k_agg(
    const int* __restrict__ rowptr, const int* __restrict__ col,
    const float* __restrict__ asrc, const float* __restrict__ adst,
    const unsigned char* __restrict__ h8,
    float* __restrict__ outf, unsigned short* __restrict__ outb,
    const float* __restrict__ scl, const float* __restrict__ shf,
    int mode, int N)
{
    __shared__ float4 exs[4][CAP];
    __shared__ int    cols[4][CAP];
    const int lane = threadIdx.x & 63;
    const int wv   = threadIdx.x >> 6;
    const int d = (blockIdx.x << 2) + wv;
    if (d >= N) return;
    const int r0  = rowptr[d];
    const int deg = rowptr[d + 1] - r0;        // >= 1 (self-loop)

    const float4 ad4 = ((const float4*)adst)[d];
    const float4* __restrict__ as4 = (const float4*)asrc;

    // pass A: exp(lrelu(logit)) -> LDS, per-head sum
    float sm0 = 0.f, sm1 = 0.f, sm2 = 0.f, sm3 = 0.f;
    for (int j = lane; j < deg; j += 64) {
        int s = col[r0 + j];
        float4 a = as4[s];
        float e0 = __expf(lrelu(a.x + ad4.x));
        float e1 = __expf(lrelu(a.y + ad4.y));
        float e2 = __expf(lrelu(a.z + ad4.z));
        float e3 = __expf(lrelu(a.w + ad4.w));
        if (j < CAP) { cols[wv][j] = s; exs[wv][j] = make_float4(e0, e1, e2, e3); }
        sm0 += e0; sm1 += e1; sm2 += e2; sm3 += e3;
    }
    #pragma unroll
    for (int o = 1; o < 64; o <<= 1) {
        sm0 += __shfl_xor(sm0, o, 64);
        sm1 += __shfl_xor(sm1, o, 64);
        sm2 += __shfl_xor(sm2, o, 64);
        sm3 += __shfl_xor(sm3, o, 64);
    }
    const float i0 = 0.25f / sm0, i1 = 0.25f / sm1, i2 = 0.25f / sm2, i3 = 0.25f / sm3;

    // pass B: packed head-pair accumulation (2 chains for ILP)
    const unsigned int* __restrict__ hu = (const unsigned int*)h8;
    f32x2 accA01 = {0.f, 0.f}, accA23 = {0.f, 0.f};
    f32x2 accB01 = {0.f, 0.f}, accB23 = {0.f, 0.f};
    if (deg <= CAP) {
        int j = 0;
        for (; j + 3 < deg; j += 4) {
            int sA = cols[wv][j],     sB = cols[wv][j + 1];
            int sC = cols[wv][j + 2], sD = cols[wv][j + 3];
            unsigned int vA = hu[(size_t)sA * 64 + lane];
            unsigned int vB = hu[(size_t)sB * 64 + lane];
            unsigned int vC = hu[(size_t)sC * 64 + lane];
            unsigned int vD = hu[(size_t)sD * 64 + lane];
            float4 wA = exs[wv][j],     wB = exs[wv][j + 1];
            float4 wC = exs[wv][j + 2], wD = exs[wv][j + 3];
            f32x2 lA = __builtin_amdgcn_cvt_pk_f32_fp8(vA, false), hA = __builtin_amdgcn_cvt_pk_f32_fp8(vA, true);
            f32x2 lB = __builtin_amdgcn_cvt_pk_f32_fp8(vB, false), hB = __builtin_amdgcn_cvt_pk_f32_fp8(vB, true);
            f32x2 lC = __builtin_amdgcn_cvt_pk_f32_fp8(vC, false), hC = __builtin_amdgcn_cvt_pk_f32_fp8(vC, true);
            f32x2 lD = __builtin_amdgcn_cvt_pk_f32_fp8(vD, false), hD = __builtin_amdgcn_cvt_pk_f32_fp8(vD, true);
            accA01 += (f32x2){wA.x, wA.y} * lA; accA23 += (f32x2){wA.z, wA.w} * hA;
            accB01 += (f32x2){wB.x, wB.y} * lB; accB23 += (f32x2){wB.z, wB.w} * hB;
            accA01 += (f32x2){wC.x, wC.y} * lC; accA23 += (f32x2){wC.z, wC.w} * hC;
            accB01 += (f32x2){wD.x, wD.y} * lD; accB23 += (f32x2){wD.z, wD.w} * hD;
        }
        for (; j < deg; ++j) {
            int s = cols[wv][j];
            unsigned int v = hu[(size_t)s * 64 + lane];
            float4 w = exs[wv][j];
            f32x2 lo = __builtin_amdgcn_cvt_pk_f32_fp8(v, false), hi = __builtin_amdgcn_cvt_pk_f32_fp8(v, true);
            accA01 += (f32x2){w.x, w.y} * lo; accA23 += (f32x2){w.z, w.w} * hi;
        }
    } else {                                     // rare: deg > CAP, recompute weights
        for (int j = 0; j < deg; ++j) {
            int s; float4 w;
            if (j < CAP) { s = cols[wv][j]; w = exs[wv][j]; }
            else {
                s = col[r0 + j];
                float4 a = as4[s];
                w.x = __expf(lrelu(a.x + ad4.x)); w.y = __expf(lrelu(a.y + ad4.y));
                w.z = __expf(lrelu(a.z + ad4.z)); w.w = __expf(lrelu(a.w + ad4.w));
            }
            unsigned int v = hu[(size_t)s * 64 + lane];
            f32x2 lo = __builtin_amdgcn_cvt_pk_f32_fp8(v, false), hi = __builtin_amdgcn_cvt_pk_f32_fp8(v, true);
            accA01 += (f32x2){w.x, w.y} * lo; accA23 += (f32x2){w.z, w.w} * hi;
        }
    }
    f32x2 s01 = accA01 + accB01;
    f32x2 s23 = accA23 + accB23;
    float acc = s01.x * i0 + s01.y * i1 + s23.x * i2 + s23.y * i3;

    if (mode) {
        float v = fmaxf(acc * scl[lane] + shf[lane], 0.f);
        outb[(size_t)d * 64 + lane] = f2us(v);
    } else {
        outf[(size_t)d * 64 + lane] = acc;
    }
}

// ---------------------------------------------------------------- pool (register run-accumulation;
// ~1 atomic per run per wave — avoids the same-address storm of per-node atomics)
__global__ __launch_bounds__(256) void k_pool(
    const float* __restrict__ outacc,
    const float* __restrict__ scl2, const float* __restrict__ shf2,
    const int* __restrict__ batch,
    float* __restrict__ pool, int N)
{
    const int lane = threadIdx.x & 63;
    const int wave = threadIdx.x >> 6;
    const int base = blockIdx.x * PNODES;
    int end = base + PNODES; if (end > N) end = N;

    const float scale = scl2[lane];
    const float shift = shf2[lane];

    float acc = 0.f;
    int cur = -1;
    for (int n = base + wave; n < end; n += 4) {
        int gr = batch[n];
        if (gr != cur) {
            if (cur >= 0) atomicAdd(&pool[(size_t)cur * 64 + lane], acc);
            cur = gr; acc = 0.f;
        }
        float v = fmaxf(outacc[(size_t)n * 64 + lane] * scale + shift, 0.f);
        acc += v;
    }
    if (cur >= 0) atomicAdd(&pool[(size_t)cur * 64 + lane], acc);
}

// ---------------------------------------------------------------- head
__global__ void k_head(const float* __restrict__ pool,
                       const int* __restrict__ gstart, const int* __restrict__ gend,
                       const float* __restrict__ fc1w, const float* __restrict__ fc1b,
                       const float* __restrict__ fc2w, const float* __restrict__ fc2b,
                       float* __restrict__ out)
{
    int g = blockIdx.x;
    int t = threadIdx.x;  // 64 threads
    __shared__ float emb[64];
    __shared__ float z1[32];
    float c = fmaxf((float)(gend[g] - gstart[g]), 1.0f);   // empty groups: pool row is 0 -> emb 0
    emb[t] = pool[g * 64 + t] / c;
    __syncthreads();
    if (t < 32) {
        float s = fc1b[t];
        for (int k = 0; k < 64; ++k) s += emb[k] * fc1w[k * 32 + t];
        z1[t] = fmaxf(s, 0.f);
    }
    __syncthreads();
    if (t < 32) {
        float o = fc2b[t];
        for (int j = 0; j < 32; ++j) o += z1[j] * fc2w[j * 32 + t];
        out[g * 32 + t] = o;
    }
}

// ---------------------------------------------------------------- launch
extern "C" void kernel_launch(void* const* d_in, const int* in_sizes, int n_in,
                              void* d_out, int out_size, void* d_ws, size_t ws_size,
                              hipStream_t stream)
{
    const float* x    = (const float*)d_in[0];
    const int*   ei   = (const int*)d_in[1];
    const int*   batch= (const int*)d_in[2];
    const float* ing  = (const float*)d_in[3];
    const float* inb  = (const float*)d_in[4];
    const float* inm  = (const float*)d_in[5];
    const float* inv  = (const float*)d_in[6];
    const float* W1   = (const float*)d_in[7];
    const float* as1  = (const float*)d_in[8];
    const float* ad1  = (const float*)d_in[9];
    const float* b1   = (const float*)d_in[10];
    const float* bn1g = (const float*)d_in[11];
    const float* bn1b = (const float*)d_in[12];
    const float* bn1m = (const float*)d_in[13];
    const float* bn1v = (const float*)d_in[14];
    const float* W2   = (const float*)d_in[15];
    const float* as2  = (const float*)d_in[16];
    const float* ad2  = (const float*)d_in[17];
    const float* b2   = (const float*)d_in[18];
    const float* bn2g = (const float*)d_in[19];
    const float* bn2b = (const float*)d_in[20];
    const float* bn2m = (const float*)d_in[21];
    const float* bn2v = (const float*)d_in[22];
    const float* fc1w = (const float*)d_in[23];
    const float* fc1b = (const float*)d_in[24];
    const float* fc2w = (const float*)d_in[25];
    const float* fc2b = (const float*)d_in[26];

    const int N = in_sizes[0] / DIN;
    const int E = in_sizes[1] / 2;
    const int G = out_size / DOUT;
    const int Etot = E + N;

    // bucket shift: smallest with (N-1)>>bshift < NBUCK
    int bshift = 0;
    while ((N >> bshift) >= NBUCK) ++bshift;
    // per-bucket arena capacity: expected density * 1.25 + slack
    const int cap = (int)(((long long)Etot << bshift) / N * 5 / 4) + 512;

    // workspace layout — ~45 MB
    unsigned char* h8 = (unsigned char*)d_ws;             // N*256 fp8 (transposed [n][c][hd])
    float* asrc   = (float*)(h8 + (size_t)N * 256);       // N*4
    float* adst   = asrc + (size_t)N * NH;                // N*4
    unsigned short* Wt    = (unsigned short*)(adst + (size_t)N * NH); // 256*128
    unsigned short* Wt2   = Wt + 256 * DIN;               // 256*64
    unsigned short* Wast1 = Wt2 + 256 * DHID;             // 16*128
    unsigned short* Wast2 = Wast1 + 16 * DIN;             // 16*64
    float* scl1   = (float*)(Wast2 + 16 * DHID);          // 64
    float* shf1   = scl1 + DHID;                          // 64
    float* scl2   = shf1 + DHID;                          // 64 (BN2 fold)
    float* shf2   = scl2 + DHID;                          // 64
    float* sclX   = shf2 + DHID;                          // 128 (input-BN scale)
    float* shfX   = sclX + DIN;                           // 128 (input-BN shift)
    float* outacc = shfX + DIN;                           // N*64 f32
    unsigned short* A2 = (unsigned short*)outacc;         // alias: N*64 bf16 (layer-1 agg out)
    int*   deg    = (int*)(outacc + (size_t)N * DHID);    // N
    int*   rowptr = deg + N;                              // N+1
    int*   cursor = rowptr + N + 1;                       // N
    int*   col    = cursor + N;                           // E+N
    float* pool   = (float*)(col + Etot);                 // G*64
    int*   gstart = (int*)(pool + (size_t)G * DHID);      // G (group run start)
    int*   gend   = gstart + G;                           // G (group run end)
    int*   bsum   = gend + G;                             // <=256
    int*   bcur   = (int*)(((size_t)(bsum + 256) + 63) & ~(size_t)63); // NBUCK*BSTR (line-padded)
    unsigned long long* arena =
        (unsigned long long*)(((size_t)(bcur + NBUCK * BSTR) + 7) & ~(size_t)7); // NBUCK*cap*8B

    const int npool = G * DHID;
    const int nScanBlk = (N + 255) / 256;
    dim3 b256(256);

    // ---- fused init + weight prep (BN folds + sorted-boundary group counts)
    int setupTot = N;
    if (setupTot < npool) setupTot = npool;
    if (setupTot < 256 * DIN) setupTot = 256 * DIN;
    k_setup<<<(setupTot + 255) / 256, b256, 0, stream>>>(
        deg, pool, bcur, N, npool,
        batch, gstart, gend,
        ing, inb, inm, inv, W1, W2, as1, ad1, as2, ad2,
        b1, bn1g, bn1b, bn1m, bn1v,
        b2, bn2g, bn2b, bn2m, bn2v,
        Wt, Wt2, Wast1, Wast2, scl1, shf1, scl2, shf2, sclX, shfX);

    // ---- CSR build (E real edges + N self-loops)
    k_part<<<(Etot + EPB - 1) / EPB, b256, 0, stream>>>(ei, E, N, bshift, arena, bcur, deg, cap);
    k_scan_a<<<nScanBlk, b256, 0, stream>>>(deg, rowptr, bsum, N);
    k_scan_c2<<<nScanBlk, b256, 0, stream>>>(rowptr, cursor, bsum, N, Etot, nScanBlk);
    {
        dim3 gFill(NBUCK, (cap + 255) / 256);
        k_fill2<<<gFill, b256, 0, stream>>>(arena, bcur, cap, cursor, col);
    }

    // ---- layer 1 (MFMA, fused input-BN + fused att); agg writes bf16 A2 (bias+BN1+ReLU fused)
    k_gemm1<<<(N + GM - 1) / GM, b256, 0, stream>>>(x, sclX, shfX, Wt, Wast1, h8, asrc, adst, N);
    k_agg<<<(N + 3) / 4, b256, 0, stream>>>(rowptr, col, asrc, adst, h8,
                                            (float*)nullptr, A2, scl1, shf1, 1, N);

    // ---- layer 2 (MFMA, fused att); agg writes raw f32 for pool
    k_gemm2<<<(N + GM - 1) / GM, b256, 0, stream>>>(A2, Wt2, Wast2, h8, asrc, adst, N);
    k_agg<<<(N + 3) / 4, b256, 0, stream>>>(rowptr, col, asrc, adst, h8,
                                            outacc, (unsigned short*)nullptr,
                                            (const float*)nullptr, (const float*)nullptr, 0, N);

    // ---- pool + head
    k_pool<<<(N + PNODES - 1) / PNODES, b256, 0, stream>>>(outacc, scl2, shf2, batch, pool, N);
    k_head<<<G, 64, 0, stream>>>(pool, gstart, gend, fc1w, fc1b, fc2w, fc2b, (float*)d_out);
}